// Round 16
// baseline (1144.634 us; speedup 1.0000x reference)
//
#include <hip/hip_runtime.h>

typedef unsigned short u16;
typedef unsigned int u32;
typedef __bf16 bf16x8 __attribute__((ext_vector_type(8)));
typedef float f32x4 __attribute__((ext_vector_type(4)));

#define L_ 4
#define D_ 768
#define T_ 1024
#define B_ 2
#define H_ 12
#define DK_ 64
#define FF_ 3072
#define V_ 50257

__device__ __forceinline__ float bf2f(u16 u){ return __uint_as_float(((unsigned)u) << 16); }
__device__ __forceinline__ u16 f2bf(float f){
  unsigned x = __float_as_uint(f);
  return (u16)((x + 0x7fffu + ((x >> 16) & 1u)) >> 16);   // RNE
}

// ---- input dtype probe (HW-proven f32; kept as insurance) ----
__global__ __launch_bounds__(256) void detect_k(const u16* __restrict__ w, int* __restrict__ flag){
  __shared__ int s;
  if (threadIdx.x == 0) s = 0;
  __syncthreads();
  int bad = 0;
  for (int j = threadIdx.x; j < 4096; j += 256){
    int e = (w[j] >> 7) & 0xFF;
    if (e >= 0xC0) bad = 1;
  }
  if (bad) atomicOr(&s, 1);
  __syncthreads();
  if (threadIdx.x == 0) flag[0] = s;
}

__device__ __forceinline__ float rdin(const void* p, long i, bool wf){
  return wf ? ((const float*)p)[i] : bf2f(((const u16*)p)[i]);
}

// ---------------- embedding ----------------
__global__ __launch_bounds__(256) void embed_k(const int* __restrict__ ids,
    const void* __restrict__ tok, const void* __restrict__ pos, float* __restrict__ x,
    const int* __restrict__ dflag){
  bool wf = dflag[0] != 0;
  int row = blockIdx.x; int t = row & (T_-1);
  long id = ids[row];
  float* xr = x + (size_t)row * D_;
  for (int d = threadIdx.x; d < D_; d += 256)
    xr[d] = rdin(tok, id * (long)D_ + d, wf) + rdin(pos, (long)t * D_ + d, wf);
}

// ---------------- layernorm: f32 x -> bf16 h ----------------
__global__ __launch_bounds__(256) void ln_k(const float* __restrict__ x,
    const void* __restrict__ g, const void* __restrict__ bb, long goff, u16* __restrict__ out,
    const int* __restrict__ dflag){
  __shared__ float red[8];
  bool wf = dflag[0] != 0;
  int row = blockIdx.x, tid = threadIdx.x;
  const float* xr = x + (size_t)row * D_;
  float v[3]; float s = 0.f, s2 = 0.f;
  #pragma unroll
  for (int i = 0; i < 3; ++i){ float t = xr[tid + i*256]; v[i] = t; s += t; s2 += t*t; }
  #pragma unroll
  for (int o = 1; o < 64; o <<= 1){ s += __shfl_xor(s, o, 64); s2 += __shfl_xor(s2, o, 64); }
  if ((tid & 63) == 0){ red[tid >> 6] = s; red[(tid >> 6) + 4] = s2; }
  __syncthreads();
  s  = red[0] + red[1] + red[2] + red[3];
  s2 = red[4] + red[5] + red[6] + red[7];
  float mean = s * (1.f / D_);
  float var  = s2 * (1.f / D_) - mean * mean;
  float rstd = rsqrtf(var + 1e-5f);
  u16* orow = out + (size_t)row * D_;
  #pragma unroll
  for (int i = 0; i < 3; ++i){
    int d = tid + i*256;
    orow[d] = f2bf((v[i] - mean) * rstd * rdin(g, goff + d, wf) + rdin(bb, goff + d, wf));
  }
}

// ---------------- fused flash attention (ALL layers); emits per-row (m,l) stats ----------------
__global__ __launch_bounds__(256) void fattn_k(const u16* __restrict__ qkv, u16* __restrict__ ctx,
                                               float* __restrict__ stats){
  __shared__ __align__(16) u16 Qs[64][72];   // later reused as P
  __shared__ __align__(16) u16 Ks[64][72];
  __shared__ __align__(16) u16 Vt[64][72];   // V transposed: [d][k]
  int qb = 15 - blockIdx.x;
  int bh = blockIdx.y;
  int b = bh / H_, h = bh % H_;
  const u16* base = qkv + (size_t)b * T_ * 3*D_;
  int qoff = h*64, koff = D_ + h*64, voff = 2*D_ + h*64;
  int tid = threadIdx.x, lane = tid & 63, w = tid >> 6;
  int sr = tid >> 3, sc = (tid & 7) << 3;
  int l15 = lane & 15, lg = lane >> 4;

  {
    const u16* gq = base + (size_t)(qb*64 + sr) * 3*D_ + qoff + sc;
    *(int4*)(&Qs[sr][sc])      = *(const int4*)gq;
    *(int4*)(&Qs[sr + 32][sc]) = *(const int4*)(gq + (size_t)32 * 3*D_);
  }
  __syncthreads();
  bf16x8 aq[2];
  #pragma unroll
  for (int kk = 0; kk < 2; ++kk)
    aq[kk] = *(const bf16x8*)(&Qs[w*16 + l15][kk*32 + lg*8]);

  f32x4 oacc[4];
  #pragma unroll
  for (int i = 0; i < 4; ++i) oacc[i] = (f32x4){0.f,0.f,0.f,0.f};
  float m_run[4] = {-1e30f,-1e30f,-1e30f,-1e30f};
  float l_run[4] = {0.f,0.f,0.f,0.f};

  for (int kb = 0; kb <= qb; ++kb){
    __syncthreads();
    {
      const u16* gk = base + (size_t)(kb*64 + sr) * 3*D_ + koff + sc;
      *(int4*)(&Ks[sr][sc])      = *(const int4*)gk;
      *(int4*)(&Ks[sr + 32][sc]) = *(const int4*)(gk + (size_t)32 * 3*D_);
      const u16* gv = base + (size_t)(kb*64 + sr) * 3*D_ + voff + sc;
      u16 tmp[8];
      *(int4*)tmp = *(const int4*)gv;
      #pragma unroll
      for (int j = 0; j < 8; ++j) Vt[sc + j][sr] = tmp[j];
      *(int4*)tmp = *(const int4*)(gv + (size_t)32 * 3*D_);
      #pragma unroll
      for (int j = 0; j < 8; ++j) Vt[sc + j][sr + 32] = tmp[j];
    }
    __syncthreads();
    f32x4 sacc[4];
    #pragma unroll
    for (int i = 0; i < 4; ++i) sacc[i] = (f32x4){0.f,0.f,0.f,0.f};
    #pragma unroll
    for (int kk = 0; kk < 2; ++kk){
      #pragma unroll
      for (int ni = 0; ni < 4; ++ni){
        bf16x8 bk = *(const bf16x8*)(&Ks[ni*16 + l15][kk*32 + lg*8]);
        sacc[ni] = __builtin_amdgcn_mfma_f32_16x16x32_bf16(aq[kk], bk, sacc[ni], 0, 0, 0);
      }
    }
    #pragma unroll
    for (int ni = 0; ni < 4; ++ni)
      #pragma unroll
      for (int r = 0; r < 4; ++r){
        float s = sacc[ni][r] * 0.125f;
        if (kb == qb){
          int rowL = w*16 + lg*4 + r, colL = ni*16 + l15;
          if (colL > rowL) s = -1e30f;
        }
        sacc[ni][r] = s;
      }
    float mx[4], ps[4];
    #pragma unroll
    for (int r = 0; r < 4; ++r){
      float m = fmaxf(fmaxf(sacc[0][r], sacc[1][r]), fmaxf(sacc[2][r], sacc[3][r]));
      #pragma unroll
      for (int o = 1; o < 16; o <<= 1) m = fmaxf(m, __shfl_xor(m, o, 64));
      mx[r] = m;
    }
    #pragma unroll
    for (int r = 0; r < 4; ++r){
      float m_new = fmaxf(m_run[r], mx[r]);
      float alpha = expf(m_run[r] - m_new);
      float sum = 0.f;
      #pragma unroll
      for (int ni = 0; ni < 4; ++ni){
        float p = expf(sacc[ni][r] - m_new);
        sacc[ni][r] = p;
        sum += p;
      }
      #pragma unroll
      for (int o = 1; o < 16; o <<= 1) sum += __shfl_xor(sum, o, 64);
      m_run[r] = m_new;
      l_run[r] = l_run[r] * alpha + sum;
      ps[r] = alpha;
    }
    #pragma unroll
    for (int ni = 0; ni < 4; ++ni)
      #pragma unroll
      for (int r = 0; r < 4; ++r)
        oacc[ni][r] *= ps[r];
    #pragma unroll
    for (int ni = 0; ni < 4; ++ni)
      #pragma unroll
      for (int r = 0; r < 4; ++r)
        Qs[w*16 + lg*4 + r][ni*16 + l15] = f2bf(sacc[ni][r]);
    #pragma unroll
    for (int kk = 0; kk < 2; ++kk){
      bf16x8 ap = *(const bf16x8*)(&Qs[w*16 + l15][kk*32 + lg*8]);
      #pragma unroll
      for (int ni = 0; ni < 4; ++ni){
        bf16x8 bv = *(const bf16x8*)(&Vt[ni*16 + l15][kk*32 + lg*8]);
        oacc[ni] = __builtin_amdgcn_mfma_f32_16x16x32_bf16(ap, bv, oacc[ni], 0, 0, 0);
      }
    }
  }
  float inv[4];
  #pragma unroll
  for (int r = 0; r < 4; ++r) inv[r] = 1.f / l_run[r];
  #pragma unroll
  for (int ni = 0; ni < 4; ++ni){
    int col = h*64 + ni*16 + l15;
    #pragma unroll
    for (int r = 0; r < 4; ++r){
      int row = b*T_ + qb*64 + w*16 + lg*4 + r;
      ctx[(size_t)row * D_ + col] = f2bf(oacc[ni][r] * inv[r]);
    }
  }
  if (l15 == 0){
    float2* st = (float2*)stats;
    #pragma unroll
    for (int r = 0; r < 4; ++r){
      int row = qb*64 + w*16 + lg*4 + r;
      st[(size_t)bh * T_ + row] = make_float2(m_run[r], l_run[r]);
    }
  }
}

// ---------------- probs reconstruction (layer 3): attn = exp(QK^T/8 - m)/l, f32, full rows ----------------
__global__ __launch_bounds__(256) void probs_k(const u16* __restrict__ qkv,
    const float* __restrict__ stats, float* __restrict__ attnf){
  __shared__ __align__(16) u16 Qs[64][72];
  __shared__ __align__(16) u16 Ks[64][72];
  __shared__ float P[64][68];
  int qb = 15 - blockIdx.x;
  int bh = blockIdx.y;
  int b = bh / H_, h = bh % H_;
  const u16* base = qkv + (size_t)b * T_ * 3*D_;
  int qoff = h*64, koff = D_ + h*64;
  float* abase = attnf + (size_t)bh * T_ * T_;
  int tid = threadIdx.x, lane = tid & 63, w = tid >> 6;
  int sr = tid >> 3, sc = (tid & 7) << 3;
  int l15 = lane & 15, lg = lane >> 4;

  {
    const u16* gq = base + (size_t)(qb*64 + sr) * 3*D_ + qoff + sc;
    *(int4*)(&Qs[sr][sc])      = *(const int4*)gq;
    *(int4*)(&Qs[sr + 32][sc]) = *(const int4*)(gq + (size_t)32 * 3*D_);
  }
  __syncthreads();
  bf16x8 aq[2];
  #pragma unroll
  for (int kk = 0; kk < 2; ++kk)
    aq[kk] = *(const bf16x8*)(&Qs[w*16 + l15][kk*32 + lg*8]);
  float mrow[4], lirow[4];
  {
    const float2* st = (const float2*)stats;
    #pragma unroll
    for (int r = 0; r < 4; ++r){
      float2 s = st[(size_t)bh * T_ + qb*64 + w*16 + lg*4 + r];
      mrow[r] = s.x; lirow[r] = 1.f / s.y;
    }
  }

  for (int kb = 0; kb <= qb; ++kb){
    __syncthreads();
    {
      const u16* gk = base + (size_t)(kb*64 + sr) * 3*D_ + koff + sc;
      *(int4*)(&Ks[sr][sc])      = *(const int4*)gk;
      *(int4*)(&Ks[sr + 32][sc]) = *(const int4*)(gk + (size_t)32 * 3*D_);
    }
    __syncthreads();
    f32x4 sacc[4];
    #pragma unroll
    for (int i = 0; i < 4; ++i) sacc[i] = (f32x4){0.f,0.f,0.f,0.f};
    #pragma unroll
    for (int kk = 0; kk < 2; ++kk){
      #pragma unroll
      for (int ni = 0; ni < 4; ++ni){
        bf16x8 bk = *(const bf16x8*)(&Ks[ni*16 + l15][kk*32 + lg*8]);
        sacc[ni] = __builtin_amdgcn_mfma_f32_16x16x32_bf16(aq[kk], bk, sacc[ni], 0, 0, 0);
      }
    }
    #pragma unroll
    for (int ni = 0; ni < 4; ++ni)
      #pragma unroll
      for (int r = 0; r < 4; ++r){
        int rowL = w*16 + lg*4 + r, colL = ni*16 + l15;
        float p = expf(sacc[ni][r] * 0.125f - mrow[r]) * lirow[r];
        if (kb == qb && colL > rowL) p = 0.f;
        P[rowL][colL] = p;
      }
    __syncthreads();
    #pragma unroll
    for (int p4 = 0; p4 < 4; ++p4){
      int row = p4*16 + (tid >> 4);
      int c0 = tid & 15;
      float* dst = abase + (size_t)(qb*64 + row) * T_ + kb*64;
      #pragma unroll
      for (int j = 0; j < 4; ++j)
        dst[c0 + j*16] = P[row][c0 + j*16];
    }
  }
  for (int r = 0; r < 64; ++r){
    float* dst = abase + (size_t)(qb*64 + r) * T_;
    for (int k = (qb+1)*64 + tid; k < T_; k += 256) dst[k] = 0.f;
  }
}

// ---------------- transpose+convert (z-batched): raw [R][ldin] window -> bf16 [C][R] ----------------
__global__ __launch_bounds__(256) void transpose_k(const void* __restrict__ in, u16* __restrict__ outp,
                                                   int R, int C, int ldin, long ielem,
                                                   long zin, long zout,
                                                   const int* __restrict__ dflag){
  __shared__ u16 tile[32][33];
  bool wf = dflag[0] != 0;
  long zi = ielem + (long)blockIdx.z * zin;
  u16* op = outp + (size_t)blockIdx.z * zout;
  int c0 = blockIdx.x * 32, r0 = blockIdx.y * 32;
  int lx = threadIdx.x & 31, ly = threadIdx.x >> 5;
  #pragma unroll
  for (int i = 0; i < 4; ++i){
    int r = r0 + ly + i*8, c = c0 + lx;
    tile[ly + i*8][lx] = (c < C) ? f2bf(rdin(in, zi + (long)r * ldin + c, wf)) : (u16)0;
  }
  __syncthreads();
  #pragma unroll
  for (int i = 0; i < 4; ++i){
    int c = c0 + ly + i*8, r = r0 + lx;
    if (c < C) op[(size_t)c * R + r] = tile[lx][ly + i*8];
  }
}

// ---------------- qkv bias concat -> bf16 [L][2304] ----------------
__global__ __launch_bounds__(256) void bcat_k(const void* __restrict__ bq, const void* __restrict__ bk,
    const void* __restrict__ bv, u16* __restrict__ outp, const int* __restrict__ dflag){
  bool wf = dflag[0] != 0;
  int l = blockIdx.x;
  for (int j = threadIdx.x; j < 3*D_; j += 256){
    float v;
    if (j < D_)        v = rdin(bq, (long)l*D_ + j, wf);
    else if (j < 2*D_) v = rdin(bk, (long)l*D_ + j - D_, wf);
    else               v = rdin(bv, (long)l*D_ + j - 2*D_, wf);
    outp[(size_t)l*3*D_ + j] = f2bf(v);
  }
}

// ---------------- 64-tile GEMM (wo, ff2): gload_lds + swizzle ----------------
// EPI: 0 bf16 store, 1 gelu->bf16, 2 f32 residual +=.
template<int EPI>
__global__ __launch_bounds__(256) void gemm_k(
    const u16* __restrict__ A, const u16* __restrict__ W, const void* __restrict__ bias,
    long belem,
    u16* __restrict__ Cbf, float* __restrict__ Cf32, const int* __restrict__ dflag,
    int N, int K, int lda, int ldw, int ldc)
{
  int m0 = blockIdx.y * 64;
  int n0 = blockIdx.x * 64;
  const bool wf = dflag && (dflag[0] != 0);

  __shared__ __align__(16) u16 SMEM[8192];
  u16* As = SMEM;
  u16* Ws = SMEM + 4096;

  int tid = threadIdx.x;
  int lane = tid & 63, wid = tid >> 6;
  int wr = wid >> 1, wc = wid & 1;
  int l15 = lane & 15, lg = lane >> 4;
  int l8 = lane >> 3;
  int sl = (lane & 7) ^ l8;

  f32x4 acc[2][2];
  #pragma unroll
  for (int i = 0; i < 2; ++i)
    #pragma unroll
    for (int j = 0; j < 2; ++j) acc[i][j] = (f32x4){0.f, 0.f, 0.f, 0.f};

  for (int k0 = 0; k0 < K; k0 += 64){
    #pragma unroll
    for (int i = 0; i < 2; ++i){
      int rb = i*32 + wid*8;
      const u16* ga = A + (size_t)(m0 + rb + l8) * lda + k0 + sl*8;
      __builtin_amdgcn_global_load_lds((const __attribute__((address_space(1))) void*)ga,
          (__attribute__((address_space(3))) void*)(As + rb*64), 16, 0, 0);
      const u16* gw = W + (size_t)(n0 + rb + l8) * ldw + k0 + sl*8;
      __builtin_amdgcn_global_load_lds((const __attribute__((address_space(1))) void*)gw,
          (__attribute__((address_space(3))) void*)(Ws + rb*64), 16, 0, 0);
    }
    __syncthreads();
    #pragma unroll
    for (int kk = 0; kk < 2; ++kk){
      int slot = kk*4 + lg;
      bf16x8 af[2], bfr[2];
      #pragma unroll
      for (int mi = 0; mi < 2; ++mi){
        int r = wr*32 + mi*16 + l15;
        af[mi] = *(const bf16x8*)(As + r*64 + ((slot ^ (r & 7)) << 3));
      }
      #pragma unroll
      for (int ni = 0; ni < 2; ++ni){
        int r = wc*32 + ni*16 + l15;
        bfr[ni] = *(const bf16x8*)(Ws + r*64 + ((slot ^ (r & 7)) << 3));
      }
      #pragma unroll
      for (int mi = 0; mi < 2; ++mi)
        #pragma unroll
        for (int ni = 0; ni < 2; ++ni)
          acc[mi][ni] = __builtin_amdgcn_mfma_f32_16x16x32_bf16(af[mi], bfr[ni], acc[mi][ni], 0, 0, 0);
    }
    __syncthreads();
  }

  #pragma unroll
  for (int ni = 0; ni < 2; ++ni){
    int col = n0 + wc*32 + ni*16 + l15;
    float bvv = 0.f;
    if (bias) bvv = wf ? ((const float*)bias)[belem + col] : bf2f(((const u16*)bias)[belem + col]);
    #pragma unroll
    for (int mi = 0; mi < 2; ++mi){
      int rbase = m0 + wr*32 + mi*16 + (lg << 2);
      #pragma unroll
      for (int r = 0; r < 4; ++r){
        int row = rbase + r;
        float v = acc[mi][ni][r] + bvv;
        size_t idx = (size_t)row * ldc + col;
        if (EPI == 0)      Cbf[idx] = f2bf(v);
        else if (EPI == 1){ float gg = 0.5f * v * (1.f + erff(v * 0.70710678118654752f)); Cbf[idx] = f2bf(gg); }
        else               Cf32[idx] += v;
      }
    }
  }
}

// ---------------- 128(M)x64(N)-tile GEMM (qkv, ff1): higher A-reuse ----------------
// 4 waves; wave wid owns rows wid*32..+32, all 64 cols. 24KB LDS.
template<int EPI>
__global__ __launch_bounds__(256) void gemmw_k(
    const u16* __restrict__ A, const u16* __restrict__ W, const void* __restrict__ bias,
    long belem,
    u16* __restrict__ Cbf, float* __restrict__ Cf32, const int* __restrict__ dflag,
    int N, int K, int lda, int ldw, int ldc)
{
  int m0 = blockIdx.y * 128;
  int n0 = blockIdx.x * 64;
  const bool wf = dflag && (dflag[0] != 0);

  __shared__ __align__(16) u16 SMEM[12288];   // As 128x64 (16KB) + Ws 64x64 (8KB)
  u16* As = SMEM;
  u16* Ws = SMEM + 8192;

  int tid = threadIdx.x;
  int lane = tid & 63, wid = tid >> 6;
  int l15 = lane & 15, lg = lane >> 4;
  int l8 = lane >> 3;
  int sl = (lane & 7) ^ l8;

  f32x4 acc[2][4];
  #pragma unroll
  for (int i = 0; i < 2; ++i)
    #pragma unroll
    for (int j = 0; j < 4; ++j) acc[i][j] = (f32x4){0.f, 0.f, 0.f, 0.f};

  for (int k0 = 0; k0 < K; k0 += 64){
    #pragma unroll
    for (int j = 0; j < 4; ++j){
      int rb = j*32 + wid*8;                  // 0..127 over j,wid
      const u16* ga = A + (size_t)(m0 + rb + l8) * lda + k0 + sl*8;
      __builtin_amdgcn_global_load_lds((const __attribute__((address_space(1))) void*)ga,
          (__attribute__((address_space(3))) void*)(As + rb*64), 16, 0, 0);
    }
    #pragma unroll
    for (int i = 0; i < 2; ++i){
      int rb = i*32 + wid*8;
      const u16* gw = W + (size_t)(n0 + rb + l8) * ldw + k0 + sl*8;
      __builtin_amdgcn_global_load_lds((const __attribute__((address_space(1))) void*)gw,
          (__attribute__((address_space(3))) void*)(Ws + rb*64), 16, 0, 0);
    }
    __syncthreads();
    #pragma unroll
    for (int kk = 0; kk < 2; ++kk){
      int slot = kk*4 + lg;
      bf16x8 af[2], bfr[4];
      #pragma unroll
      for (int mi = 0; mi < 2; ++mi){
        int r = wid*32 + mi*16 + l15;
        af[mi] = *(const bf16x8*)(As + r*64 + ((slot ^ (r & 7)) << 3));
      }
      #pragma unroll
      for (int ni = 0; ni < 4; ++ni){
        int r = ni*16 + l15;
        bfr[ni] = *(const bf16x8*)(Ws + r*64 + ((slot ^ (r & 7)) << 3));
      }
      #pragma unroll
      for (int mi = 0; mi < 2; ++mi)
        #pragma unroll
        for (int ni = 0; ni < 4; ++ni)
          acc[mi][ni] = __builtin_amdgcn_mfma_f32_16x16x32_bf16(af[mi], bfr[ni], acc[mi][ni], 0, 0, 0);
    }
    __syncthreads();
  }

  #pragma unroll
  for (int ni = 0; ni < 4; ++ni){
    int col = n0 + ni*16 + l15;
    float bvv = 0.f;
    if (bias) bvv = wf ? ((const float*)bias)[belem + col] : bf2f(((const u16*)bias)[belem + col]);
    #pragma unroll
    for (int mi = 0; mi < 2; ++mi){
      int rbase = m0 + wid*32 + mi*16 + (lg << 2);
      #pragma unroll
      for (int r = 0; r < 4; ++r){
        int row = rbase + r;
        float v = acc[mi][ni][r] + bvv;
        size_t idx = (size_t)row * ldc + col;
        if (EPI == 0)      Cbf[idx] = f2bf(v);
        else if (EPI == 1){ float gg = 0.5f * v * (1.f + erff(v * 0.70710678118654752f)); Cbf[idx] = f2bf(gg); }
        else               Cf32[idx] += v;
      }
    }
  }
}

// ---------------- 128x128 m97-structure GEMM: projection only ----------------
__global__ __launch_bounds__(256) void gemm128_k(
    const u16* __restrict__ A, const u16* __restrict__ Wt, float* __restrict__ C,
    int N, int K, int lda, int ldw, int ldc)
{
  int m0 = blockIdx.x * 128;
  int n0 = blockIdx.y * 128;
  __shared__ __align__(16) u16 SM[2 * 128 * 64];
  u16* As = SM;
  u16* Ws = SM + 128 * 64;

  int tid = threadIdx.x, lane = tid & 63, wid = tid >> 6;
  int wr = wid >> 1, wc = wid & 1;
  int l8 = lane >> 3;
  int sl = (lane & 7) ^ l8;

  f32x4 acc[4][4];
  #pragma unroll
  for (int i = 0; i < 4; ++i)
    #pragma unroll
    for (int j = 0; j < 4; ++j) acc[i][j] = (f32x4){0.f, 0.f, 0.f, 0.f};

  for (int k0 = 0; k0 < K; k0 += 64){
    #pragma unroll
    for (int j = 0; j < 4; ++j){
      int c = wid * 4 + j;
      const u16* ga = A  + (size_t)(m0 + 8*c + l8) * lda + k0 + sl*8;
      const u16* gw = Wt + (size_t)(n0 + 8*c + l8) * ldw + k0 + sl*8;
      __builtin_amdgcn_global_load_lds((const __attribute__((address_space(1))) void*)ga,
          (__attribute__((address_space(3))) void*)(As + c*512), 16, 0, 0);
      __builtin_amdgcn_global_load_lds((const __attribute__((address_space(1))) void*)gw,
          (__attribute__((address_space(3))) void*)(Ws + c*512), 16, 0, 0);
    }
    __syncthreads();
    #pragma unroll
    for (int kk = 0; kk < 2; ++kk){
      int slot = kk*4 + (lane >> 4);
      bf16x8 av[4], bv[4];
      #pragma unroll
      for (int mi = 0; mi < 4; ++mi){
        int r = wr*64 + mi*16 + (lane & 15);
        av[mi] = *(const bf16x8*)(As + r*64 + ((slot ^ (r & 7)) << 3));
      }
      #pragma unroll
      for (int ni = 0; ni < 4; ++ni){
        int r = wc*64 + ni*16 + (lane & 15);
        bv[ni] = *(const bf16x8*)(Ws + r*64 + ((slot ^ (r & 7)) << 3));
      }
      #pragma unroll
      for (int mi = 0; mi < 4; ++mi)
        #pragma unroll
        for (int ni = 0; ni < 4; ++ni)
          acc[mi][ni] = __builtin_amdgcn_mfma_f32_16x16x32_bf16(av[mi], bv[ni], acc[mi][ni], 0, 0, 0);
    }
    __syncthreads();
  }

  float* flds = (float*)SM;
  #pragma unroll
  for (int hf = 0; hf < 2; ++hf){
    if (wr == hf){
      #pragma unroll
      for (int mi = 0; mi < 4; ++mi){
        int rb = mi*16 + ((lane >> 4) << 2);
        #pragma unroll
        for (int ni = 0; ni < 4; ++ni){
          int colL = wc*64 + ni*16 + (lane & 15);
          #pragma unroll
          for (int r = 0; r < 4; ++r)
            flds[(rb + r)*128 + colL] = acc[mi][ni][r];
        }
      }
    }
    __syncthreads();
    int c = tid & 127;
    int gc = n0 + c;
    if (gc < N){
      for (int rr = (tid >> 7); rr < 64; rr += 2)
        C[(size_t)(m0 + hf*64 + rr) * ldc + gc] = flds[rr*128 + c];
    }
    __syncthreads();
  }
}

extern "C" void kernel_launch(void* const* d_in, const int* in_sizes, int n_in,
                              void* d_out, int out_size, void* d_ws, size_t ws_size,
                              hipStream_t stream)
{
  (void)in_sizes; (void)n_in; (void)out_size; (void)ws_size;
  const int* ids = (const int*)d_in[0];
  const void* tok = d_in[1];  const void* pos = d_in[2];
  const void* ln1g = d_in[3]; const void* ln1b = d_in[4];
  const void* wq = d_in[5];   const void* bq = d_in[6];
  const void* wk = d_in[7];   const void* bk = d_in[8];
  const void* wv = d_in[9];   const void* bv = d_in[10];
  const void* wo = d_in[11];  const void* bo = d_in[12];
  const void* ln2g = d_in[13]; const void* ln2b = d_in[14];
  const void* w1 = d_in[15];  const void* b1 = d_in[16];
  const void* w2 = d_in[17];  const void* b2 = d_in[18];
  const void* lnfg = d_in[19]; const void* lnfb = d_in[20];
  const void* pw = d_in[21];

  char* ob = (char*)d_out;
  float* logitsF = (float*)ob;
  float* attnF   = (float*)(ob + 411705344);
  float* x    = (float*)(ob + 100663296);
  u16* qkv    = (u16*)(ob + 106954752);
  u16* ctx    = (u16*)(ob + 116391936);
  u16* ff     = (u16*)(ob + 119537664);
  u16* wT     = (u16*)(ob + 132120576);
  u16* biascat= (u16*)(ob + 188743680);
  float* stats= (float*)(ob + 188762112);        // [B*H][T] float2 (m,l)
  const long LSTR = 7077888;
  char* wsp = (char*)d_ws;
  int* dflag = (int*)wsp;
  u16* h      = (u16*)(wsp + 256);
  u16* chunkT = (u16*)(wsp + 256 + 3145728);

  const int BT = B_ * T_;
  detect_k<<<1, 256, 0, stream>>>((const u16*)tok, dflag);
  bcat_k<<<L_, 256, 0, stream>>>(bq, bk, bv, biascat, dflag);
  {
    dim3 gDD(24, 24, L_), g1(96, 24, L_), g2(24, 96, L_);
    transpose_k<<<gDD, 256, 0, stream>>>(wq, wT,            D_, D_,  D_,  0, (long)D_*D_,  LSTR, dflag);
    transpose_k<<<gDD, 256, 0, stream>>>(wk, wT + 589824,   D_, D_,  D_,  0, (long)D_*D_,  LSTR, dflag);
    transpose_k<<<gDD, 256, 0, stream>>>(wv, wT + 2*589824, D_, D_,  D_,  0, (long)D_*D_,  LSTR, dflag);
    transpose_k<<<gDD, 256, 0, stream>>>(wo, wT + 3*589824, D_, D_,  D_,  0, (long)D_*D_,  LSTR, dflag);
    transpose_k<<<g1, 256, 0, stream>>>(w1, wT + 4*589824,  D_, FF_, FF_, 0, (long)D_*FF_, LSTR, dflag);
    transpose_k<<<g2, 256, 0, stream>>>(w2, wT + 4*589824 + 2359296, FF_, D_, D_, 0, (long)FF_*D_, LSTR, dflag);
  }
  embed_k<<<BT, 256, 0, stream>>>(ids, tok, pos, x, dflag);

  dim3 gQKV(36, 16);                 // 128x64 tiles, 576 blocks
  dim3 gFF1(48, 16);                 // 128x64 tiles, 768 blocks
  dim3 gD(12, 32);                   // 64x64, 384 blocks (wo, ff2)
  dim3 gA(16, B_*H_);

  for (int l = 0; l < L_; ++l){
    long oB = (long)l * D_, oB1 = (long)l * FF_;
    u16* wl  = wT + (size_t)l * LSTR;
    u16* woT = wl + 3*589824;
    u16* w1T = wl + 4*589824;
    u16* w2T = w1T + 2359296;
    ln_k<<<BT, 256, 0, stream>>>(x, ln1g, ln1b, oB, h, dflag);
    gemmw_k<0><<<gQKV, 256, 0, stream>>>(h, wl, biascat, (long)l*3*D_, qkv, nullptr, nullptr,
        3*D_, D_, D_, D_, 3*D_);
    fattn_k<<<gA, 256, 0, stream>>>(qkv, ctx, stats);
    if (l == L_-1)
      probs_k<<<gA, 256, 0, stream>>>(qkv, stats, attnF);
    gemm_k<2><<<gD, 256, 0, stream>>>(ctx, woT, bo, oB, nullptr, x, dflag,
        D_, D_, D_, D_, D_);
    ln_k<<<BT, 256, 0, stream>>>(x, ln2g, ln2b, oB, h, dflag);
    gemmw_k<1><<<gFF1, 256, 0, stream>>>(h, w1T, b1, oB1, ff, nullptr, dflag,
        FF_, D_, D_, D_, FF_);
    gemm_k<2><<<gD, 256, 0, stream>>>(ff, w2T, b2, oB, nullptr, x, dflag,
        D_, FF_, FF_, FF_, D_);
  }
  ln_k<<<BT, 256, 0, stream>>>(x, lnfg, lnfb, 0, h, dflag);
  {
    const int CHUNK = 12544;
    int done = 0;
    while (done < V_){
      int cols = V_ - done; if (cols > CHUNK) cols = CHUNK;
      dim3 gt((cols + 31) / 32, 24);
      transpose_k<<<gt, 256, 0, stream>>>(pw, chunkT, D_, cols, V_, (long)done, 0, 0, dflag);
      dim3 gp(16, (cols + 127) / 128);
      gemm128_k<<<gp, 256, 0, stream>>>(h, chunkT, logitsF + done, cols, D_, D_, D_, V_);
      done += cols;
    }
  }
}

// Round 17
// 1113.848 us; speedup vs baseline: 1.0276x; 1.0276x over previous
//
#include <hip/hip_runtime.h>

typedef unsigned short u16;
typedef unsigned int u32;
typedef __bf16 bf16x8 __attribute__((ext_vector_type(8)));
typedef float f32x4 __attribute__((ext_vector_type(4)));

#define L_ 4
#define D_ 768
#define T_ 1024
#define B_ 2
#define H_ 12
#define DK_ 64
#define FF_ 3072
#define V_ 50257

__device__ __forceinline__ float bf2f(u16 u){ return __uint_as_float(((unsigned)u) << 16); }
__device__ __forceinline__ u16 f2bf(float f){
  unsigned x = __float_as_uint(f);
  return (u16)((x + 0x7fffu + ((x >> 16) & 1u)) >> 16);   // RNE
}

// ---- input dtype probe (HW-proven f32; kept as insurance) ----
__global__ __launch_bounds__(256) void detect_k(const u16* __restrict__ w, int* __restrict__ flag){
  __shared__ int s;
  if (threadIdx.x == 0) s = 0;
  __syncthreads();
  int bad = 0;
  for (int j = threadIdx.x; j < 4096; j += 256){
    int e = (w[j] >> 7) & 0xFF;
    if (e >= 0xC0) bad = 1;
  }
  if (bad) atomicOr(&s, 1);
  __syncthreads();
  if (threadIdx.x == 0) flag[0] = s;
}

__device__ __forceinline__ float rdin(const void* p, long i, bool wf){
  return wf ? ((const float*)p)[i] : bf2f(((const u16*)p)[i]);
}

// ---------------- embedding ----------------
__global__ __launch_bounds__(256) void embed_k(const int* __restrict__ ids,
    const void* __restrict__ tok, const void* __restrict__ pos, float* __restrict__ x,
    const int* __restrict__ dflag){
  bool wf = dflag[0] != 0;
  int row = blockIdx.x; int t = row & (T_-1);
  long id = ids[row];
  float* xr = x + (size_t)row * D_;
  for (int d = threadIdx.x; d < D_; d += 256)
    xr[d] = rdin(tok, id * (long)D_ + d, wf) + rdin(pos, (long)t * D_ + d, wf);
}

// ---------------- layernorm: f32 x -> bf16 h ----------------
__global__ __launch_bounds__(256) void ln_k(const float* __restrict__ x,
    const void* __restrict__ g, const void* __restrict__ bb, long goff, u16* __restrict__ out,
    const int* __restrict__ dflag){
  __shared__ float red[8];
  bool wf = dflag[0] != 0;
  int row = blockIdx.x, tid = threadIdx.x;
  const float* xr = x + (size_t)row * D_;
  float v[3]; float s = 0.f, s2 = 0.f;
  #pragma unroll
  for (int i = 0; i < 3; ++i){ float t = xr[tid + i*256]; v[i] = t; s += t; s2 += t*t; }
  #pragma unroll
  for (int o = 1; o < 64; o <<= 1){ s += __shfl_xor(s, o, 64); s2 += __shfl_xor(s2, o, 64); }
  if ((tid & 63) == 0){ red[tid >> 6] = s; red[(tid >> 6) + 4] = s2; }
  __syncthreads();
  s  = red[0] + red[1] + red[2] + red[3];
  s2 = red[4] + red[5] + red[6] + red[7];
  float mean = s * (1.f / D_);
  float var  = s2 * (1.f / D_) - mean * mean;
  float rstd = rsqrtf(var + 1e-5f);
  u16* orow = out + (size_t)row * D_;
  #pragma unroll
  for (int i = 0; i < 3; ++i){
    int d = tid + i*256;
    orow[d] = f2bf((v[i] - mean) * rstd * rdin(g, goff + d, wf) + rdin(bb, goff + d, wf));
  }
}

// ---------------- fused flash attention (ALL layers); emits per-row (m,l) stats ----------------
__global__ __launch_bounds__(256) void fattn_k(const u16* __restrict__ qkv, u16* __restrict__ ctx,
                                               float* __restrict__ stats){
  __shared__ __align__(16) u16 Qs[64][72];   // later reused as P
  __shared__ __align__(16) u16 Ks[64][72];
  __shared__ __align__(16) u16 Vt[64][72];   // V transposed: [d][k]
  int qb = 15 - blockIdx.x;
  int bh = blockIdx.y;
  int b = bh / H_, h = bh % H_;
  const u16* base = qkv + (size_t)b * T_ * 3*D_;
  int qoff = h*64, koff = D_ + h*64, voff = 2*D_ + h*64;
  int tid = threadIdx.x, lane = tid & 63, w = tid >> 6;
  int sr = tid >> 3, sc = (tid & 7) << 3;
  int l15 = lane & 15, lg = lane >> 4;

  {
    const u16* gq = base + (size_t)(qb*64 + sr) * 3*D_ + qoff + sc;
    *(int4*)(&Qs[sr][sc])      = *(const int4*)gq;
    *(int4*)(&Qs[sr + 32][sc]) = *(const int4*)(gq + (size_t)32 * 3*D_);
  }
  __syncthreads();
  bf16x8 aq[2];
  #pragma unroll
  for (int kk = 0; kk < 2; ++kk)
    aq[kk] = *(const bf16x8*)(&Qs[w*16 + l15][kk*32 + lg*8]);

  f32x4 oacc[4];
  #pragma unroll
  for (int i = 0; i < 4; ++i) oacc[i] = (f32x4){0.f,0.f,0.f,0.f};
  float m_run[4] = {-1e30f,-1e30f,-1e30f,-1e30f};
  float l_run[4] = {0.f,0.f,0.f,0.f};

  for (int kb = 0; kb <= qb; ++kb){
    __syncthreads();
    {
      const u16* gk = base + (size_t)(kb*64 + sr) * 3*D_ + koff + sc;
      *(int4*)(&Ks[sr][sc])      = *(const int4*)gk;
      *(int4*)(&Ks[sr + 32][sc]) = *(const int4*)(gk + (size_t)32 * 3*D_);
      const u16* gv = base + (size_t)(kb*64 + sr) * 3*D_ + voff + sc;
      u16 tmp[8];
      *(int4*)tmp = *(const int4*)gv;
      #pragma unroll
      for (int j = 0; j < 8; ++j) Vt[sc + j][sr] = tmp[j];
      *(int4*)tmp = *(const int4*)(gv + (size_t)32 * 3*D_);
      #pragma unroll
      for (int j = 0; j < 8; ++j) Vt[sc + j][sr + 32] = tmp[j];
    }
    __syncthreads();
    f32x4 sacc[4];
    #pragma unroll
    for (int i = 0; i < 4; ++i) sacc[i] = (f32x4){0.f,0.f,0.f,0.f};
    #pragma unroll
    for (int kk = 0; kk < 2; ++kk){
      #pragma unroll
      for (int ni = 0; ni < 4; ++ni){
        bf16x8 bk = *(const bf16x8*)(&Ks[ni*16 + l15][kk*32 + lg*8]);
        sacc[ni] = __builtin_amdgcn_mfma_f32_16x16x32_bf16(aq[kk], bk, sacc[ni], 0, 0, 0);
      }
    }
    #pragma unroll
    for (int ni = 0; ni < 4; ++ni)
      #pragma unroll
      for (int r = 0; r < 4; ++r){
        float s = sacc[ni][r] * 0.125f;
        if (kb == qb){
          int rowL = w*16 + lg*4 + r, colL = ni*16 + l15;
          if (colL > rowL) s = -1e30f;
        }
        sacc[ni][r] = s;
      }
    float mx[4], ps[4];
    #pragma unroll
    for (int r = 0; r < 4; ++r){
      float m = fmaxf(fmaxf(sacc[0][r], sacc[1][r]), fmaxf(sacc[2][r], sacc[3][r]));
      #pragma unroll
      for (int o = 1; o < 16; o <<= 1) m = fmaxf(m, __shfl_xor(m, o, 64));
      mx[r] = m;
    }
    #pragma unroll
    for (int r = 0; r < 4; ++r){
      float m_new = fmaxf(m_run[r], mx[r]);
      float alpha = expf(m_run[r] - m_new);
      float sum = 0.f;
      #pragma unroll
      for (int ni = 0; ni < 4; ++ni){
        float p = expf(sacc[ni][r] - m_new);
        sacc[ni][r] = p;
        sum += p;
      }
      #pragma unroll
      for (int o = 1; o < 16; o <<= 1) sum += __shfl_xor(sum, o, 64);
      m_run[r] = m_new;
      l_run[r] = l_run[r] * alpha + sum;
      ps[r] = alpha;
    }
    #pragma unroll
    for (int ni = 0; ni < 4; ++ni)
      #pragma unroll
      for (int r = 0; r < 4; ++r)
        oacc[ni][r] *= ps[r];
    #pragma unroll
    for (int ni = 0; ni < 4; ++ni)
      #pragma unroll
      for (int r = 0; r < 4; ++r)
        Qs[w*16 + lg*4 + r][ni*16 + l15] = f2bf(sacc[ni][r]);
    #pragma unroll
    for (int kk = 0; kk < 2; ++kk){
      bf16x8 ap = *(const bf16x8*)(&Qs[w*16 + l15][kk*32 + lg*8]);
      #pragma unroll
      for (int ni = 0; ni < 4; ++ni){
        bf16x8 bv = *(const bf16x8*)(&Vt[ni*16 + l15][kk*32 + lg*8]);
        oacc[ni] = __builtin_amdgcn_mfma_f32_16x16x32_bf16(ap, bv, oacc[ni], 0, 0, 0);
      }
    }
  }
  float inv[4];
  #pragma unroll
  for (int r = 0; r < 4; ++r) inv[r] = 1.f / l_run[r];
  #pragma unroll
  for (int ni = 0; ni < 4; ++ni){
    int col = h*64 + ni*16 + l15;
    #pragma unroll
    for (int r = 0; r < 4; ++r){
      int row = b*T_ + qb*64 + w*16 + lg*4 + r;
      ctx[(size_t)row * D_ + col] = f2bf(oacc[ni][r] * inv[r]);
    }
  }
  if (l15 == 0){
    float2* st = (float2*)stats;
    #pragma unroll
    for (int r = 0; r < 4; ++r){
      int row = qb*64 + w*16 + lg*4 + r;
      st[(size_t)bh * T_ + row] = make_float2(m_run[r], l_run[r]);
    }
  }
}

// ---------------- probs reconstruction (layer 3): attn = exp(QK^T/8 - m)/l, f32, full rows ----------------
__global__ __launch_bounds__(256) void probs_k(const u16* __restrict__ qkv,
    const float* __restrict__ stats, float* __restrict__ attnf){
  __shared__ __align__(16) u16 Qs[64][72];
  __shared__ __align__(16) u16 Ks[64][72];
  __shared__ float P[64][68];
  int qb = 15 - blockIdx.x;
  int bh = blockIdx.y;
  int b = bh / H_, h = bh % H_;
  const u16* base = qkv + (size_t)b * T_ * 3*D_;
  int qoff = h*64, koff = D_ + h*64;
  float* abase = attnf + (size_t)bh * T_ * T_;
  int tid = threadIdx.x, lane = tid & 63, w = tid >> 6;
  int sr = tid >> 3, sc = (tid & 7) << 3;
  int l15 = lane & 15, lg = lane >> 4;

  {
    const u16* gq = base + (size_t)(qb*64 + sr) * 3*D_ + qoff + sc;
    *(int4*)(&Qs[sr][sc])      = *(const int4*)gq;
    *(int4*)(&Qs[sr + 32][sc]) = *(const int4*)(gq + (size_t)32 * 3*D_);
  }
  __syncthreads();
  bf16x8 aq[2];
  #pragma unroll
  for (int kk = 0; kk < 2; ++kk)
    aq[kk] = *(const bf16x8*)(&Qs[w*16 + l15][kk*32 + lg*8]);
  float mrow[4], lirow[4];
  {
    const float2* st = (const float2*)stats;
    #pragma unroll
    for (int r = 0; r < 4; ++r){
      float2 s = st[(size_t)bh * T_ + qb*64 + w*16 + lg*4 + r];
      mrow[r] = s.x; lirow[r] = 1.f / s.y;
    }
  }

  for (int kb = 0; kb <= qb; ++kb){
    __syncthreads();
    {
      const u16* gk = base + (size_t)(kb*64 + sr) * 3*D_ + koff + sc;
      *(int4*)(&Ks[sr][sc])      = *(const int4*)gk;
      *(int4*)(&Ks[sr + 32][sc]) = *(const int4*)(gk + (size_t)32 * 3*D_);
    }
    __syncthreads();
    f32x4 sacc[4];
    #pragma unroll
    for (int i = 0; i < 4; ++i) sacc[i] = (f32x4){0.f,0.f,0.f,0.f};
    #pragma unroll
    for (int kk = 0; kk < 2; ++kk){
      #pragma unroll
      for (int ni = 0; ni < 4; ++ni){
        bf16x8 bk = *(const bf16x8*)(&Ks[ni*16 + l15][kk*32 + lg*8]);
        sacc[ni] = __builtin_amdgcn_mfma_f32_16x16x32_bf16(aq[kk], bk, sacc[ni], 0, 0, 0);
      }
    }
    #pragma unroll
    for (int ni = 0; ni < 4; ++ni)
      #pragma unroll
      for (int r = 0; r < 4; ++r){
        int rowL = w*16 + lg*4 + r, colL = ni*16 + l15;
        float p = expf(sacc[ni][r] * 0.125f - mrow[r]) * lirow[r];
        if (kb == qb && colL > rowL) p = 0.f;
        P[rowL][colL] = p;
      }
    __syncthreads();
    #pragma unroll
    for (int p4 = 0; p4 < 4; ++p4){
      int row = p4*16 + (tid >> 4);
      int c0 = tid & 15;
      float* dst = abase + (size_t)(qb*64 + row) * T_ + kb*64;
      #pragma unroll
      for (int j = 0; j < 4; ++j)
        dst[c0 + j*16] = P[row][c0 + j*16];
    }
  }
  for (int r = 0; r < 64; ++r){
    float* dst = abase + (size_t)(qb*64 + r) * T_;
    for (int k = (qb+1)*64 + tid; k < T_; k += 256) dst[k] = 0.f;
  }
}

// ---------------- transpose+convert (z-batched): raw [R][ldin] window -> bf16 [C][R] ----------------
__global__ __launch_bounds__(256) void transpose_k(const void* __restrict__ in, u16* __restrict__ outp,
                                                   int R, int C, int ldin, long ielem,
                                                   long zin, long zout,
                                                   const int* __restrict__ dflag){
  __shared__ u16 tile[32][33];
  bool wf = dflag[0] != 0;
  long zi = ielem + (long)blockIdx.z * zin;
  u16* op = outp + (size_t)blockIdx.z * zout;
  int c0 = blockIdx.x * 32, r0 = blockIdx.y * 32;
  int lx = threadIdx.x & 31, ly = threadIdx.x >> 5;
  #pragma unroll
  for (int i = 0; i < 4; ++i){
    int r = r0 + ly + i*8, c = c0 + lx;
    tile[ly + i*8][lx] = (c < C) ? f2bf(rdin(in, zi + (long)r * ldin + c, wf)) : (u16)0;
  }
  __syncthreads();
  #pragma unroll
  for (int i = 0; i < 4; ++i){
    int c = c0 + ly + i*8, r = r0 + lx;
    if (c < C) op[(size_t)c * R + r] = tile[lx][ly + i*8];
  }
}

// ---------------- qkv bias concat -> bf16 [L][2304] ----------------
__global__ __launch_bounds__(256) void bcat_k(const void* __restrict__ bq, const void* __restrict__ bk,
    const void* __restrict__ bv, u16* __restrict__ outp, const int* __restrict__ dflag){
  bool wf = dflag[0] != 0;
  int l = blockIdx.x;
  for (int j = threadIdx.x; j < 3*D_; j += 256){
    float v;
    if (j < D_)        v = rdin(bq, (long)l*D_ + j, wf);
    else if (j < 2*D_) v = rdin(bk, (long)l*D_ + j - D_, wf);
    else               v = rdin(bv, (long)l*D_ + j - 2*D_, wf);
    outp[(size_t)l*3*D_ + j] = f2bf(v);
  }
}

// ---------------- 64-tile GEMM (wo, ff2): gload_lds + swizzle ----------------
template<int EPI>
__global__ __launch_bounds__(256) void gemm_k(
    const u16* __restrict__ A, const u16* __restrict__ W, const void* __restrict__ bias,
    long belem,
    u16* __restrict__ Cbf, float* __restrict__ Cf32, const int* __restrict__ dflag,
    int N, int K, int lda, int ldw, int ldc)
{
  int m0 = blockIdx.y * 64;
  int n0 = blockIdx.x * 64;
  const bool wf = dflag && (dflag[0] != 0);

  __shared__ __align__(16) u16 SMEM[8192];
  u16* As = SMEM;
  u16* Ws = SMEM + 4096;

  int tid = threadIdx.x;
  int lane = tid & 63, wid = tid >> 6;
  int wr = wid >> 1, wc = wid & 1;
  int l15 = lane & 15, lg = lane >> 4;
  int l8 = lane >> 3;
  int sl = (lane & 7) ^ l8;

  f32x4 acc[2][2];
  #pragma unroll
  for (int i = 0; i < 2; ++i)
    #pragma unroll
    for (int j = 0; j < 2; ++j) acc[i][j] = (f32x4){0.f, 0.f, 0.f, 0.f};

  for (int k0 = 0; k0 < K; k0 += 64){
    #pragma unroll
    for (int i = 0; i < 2; ++i){
      int rb = i*32 + wid*8;
      const u16* ga = A + (size_t)(m0 + rb + l8) * lda + k0 + sl*8;
      __builtin_amdgcn_global_load_lds((const __attribute__((address_space(1))) void*)ga,
          (__attribute__((address_space(3))) void*)(As + rb*64), 16, 0, 0);
      const u16* gw = W + (size_t)(n0 + rb + l8) * ldw + k0 + sl*8;
      __builtin_amdgcn_global_load_lds((const __attribute__((address_space(1))) void*)gw,
          (__attribute__((address_space(3))) void*)(Ws + rb*64), 16, 0, 0);
    }
    __syncthreads();
    #pragma unroll
    for (int kk = 0; kk < 2; ++kk){
      int slot = kk*4 + lg;
      bf16x8 af[2], bfr[2];
      #pragma unroll
      for (int mi = 0; mi < 2; ++mi){
        int r = wr*32 + mi*16 + l15;
        af[mi] = *(const bf16x8*)(As + r*64 + ((slot ^ (r & 7)) << 3));
      }
      #pragma unroll
      for (int ni = 0; ni < 2; ++ni){
        int r = wc*32 + ni*16 + l15;
        bfr[ni] = *(const bf16x8*)(Ws + r*64 + ((slot ^ (r & 7)) << 3));
      }
      #pragma unroll
      for (int mi = 0; mi < 2; ++mi)
        #pragma unroll
        for (int ni = 0; ni < 2; ++ni)
          acc[mi][ni] = __builtin_amdgcn_mfma_f32_16x16x32_bf16(af[mi], bfr[ni], acc[mi][ni], 0, 0, 0);
    }
    __syncthreads();
  }

  #pragma unroll
  for (int ni = 0; ni < 2; ++ni){
    int col = n0 + wc*32 + ni*16 + l15;
    float bvv = 0.f;
    if (bias) bvv = wf ? ((const float*)bias)[belem + col] : bf2f(((const u16*)bias)[belem + col]);
    #pragma unroll
    for (int mi = 0; mi < 2; ++mi){
      int rbase = m0 + wr*32 + mi*16 + (lg << 2);
      #pragma unroll
      for (int r = 0; r < 4; ++r){
        int row = rbase + r;
        float v = acc[mi][ni][r] + bvv;
        size_t idx = (size_t)row * ldc + col;
        if (EPI == 0)      Cbf[idx] = f2bf(v);
        else if (EPI == 1){ float gg = 0.5f * v * (1.f + erff(v * 0.70710678118654752f)); Cbf[idx] = f2bf(gg); }
        else               Cf32[idx] += v;
      }
    }
  }
}

// ---------------- 128(M)x64(N)-tile GEMM (qkv, ff1) ----------------
template<int EPI>
__global__ __launch_bounds__(256) void gemmw_k(
    const u16* __restrict__ A, const u16* __restrict__ W, const void* __restrict__ bias,
    long belem,
    u16* __restrict__ Cbf, float* __restrict__ Cf32, const int* __restrict__ dflag,
    int N, int K, int lda, int ldw, int ldc)
{
  int m0 = blockIdx.y * 128;
  int n0 = blockIdx.x * 64;
  const bool wf = dflag && (dflag[0] != 0);

  __shared__ __align__(16) u16 SMEM[12288];
  u16* As = SMEM;
  u16* Ws = SMEM + 8192;

  int tid = threadIdx.x;
  int lane = tid & 63, wid = tid >> 6;
  int l15 = lane & 15, lg = lane >> 4;
  int l8 = lane >> 3;
  int sl = (lane & 7) ^ l8;

  f32x4 acc[2][4];
  #pragma unroll
  for (int i = 0; i < 2; ++i)
    #pragma unroll
    for (int j = 0; j < 4; ++j) acc[i][j] = (f32x4){0.f, 0.f, 0.f, 0.f};

  for (int k0 = 0; k0 < K; k0 += 64){
    #pragma unroll
    for (int j = 0; j < 4; ++j){
      int rb = j*32 + wid*8;
      const u16* ga = A + (size_t)(m0 + rb + l8) * lda + k0 + sl*8;
      __builtin_amdgcn_global_load_lds((const __attribute__((address_space(1))) void*)ga,
          (__attribute__((address_space(3))) void*)(As + rb*64), 16, 0, 0);
    }
    #pragma unroll
    for (int i = 0; i < 2; ++i){
      int rb = i*32 + wid*8;
      const u16* gw = W + (size_t)(n0 + rb + l8) * ldw + k0 + sl*8;
      __builtin_amdgcn_global_load_lds((const __attribute__((address_space(1))) void*)gw,
          (__attribute__((address_space(3))) void*)(Ws + rb*64), 16, 0, 0);
    }
    __syncthreads();
    #pragma unroll
    for (int kk = 0; kk < 2; ++kk){
      int slot = kk*4 + lg;
      bf16x8 af[2], bfr[4];
      #pragma unroll
      for (int mi = 0; mi < 2; ++mi){
        int r = wid*32 + mi*16 + l15;
        af[mi] = *(const bf16x8*)(As + r*64 + ((slot ^ (r & 7)) << 3));
      }
      #pragma unroll
      for (int ni = 0; ni < 4; ++ni){
        int r = ni*16 + l15;
        bfr[ni] = *(const bf16x8*)(Ws + r*64 + ((slot ^ (r & 7)) << 3));
      }
      #pragma unroll
      for (int mi = 0; mi < 2; ++mi)
        #pragma unroll
        for (int ni = 0; ni < 4; ++ni)
          acc[mi][ni] = __builtin_amdgcn_mfma_f32_16x16x32_bf16(af[mi], bfr[ni], acc[mi][ni], 0, 0, 0);
    }
    __syncthreads();
  }

  #pragma unroll
  for (int ni = 0; ni < 4; ++ni){
    int col = n0 + ni*16 + l15;
    float bvv = 0.f;
    if (bias) bvv = wf ? ((const float*)bias)[belem + col] : bf2f(((const u16*)bias)[belem + col]);
    #pragma unroll
    for (int mi = 0; mi < 2; ++mi){
      int rbase = m0 + wid*32 + mi*16 + (lg << 2);
      #pragma unroll
      for (int r = 0; r < 4; ++r){
        int row = rbase + r;
        float v = acc[mi][ni][r] + bvv;
        size_t idx = (size_t)row * ldc + col;
        if (EPI == 0)      Cbf[idx] = f2bf(v);
        else if (EPI == 1){ float gg = 0.5f * v * (1.f + erff(v * 0.70710678118654752f)); Cbf[idx] = f2bf(gg); }
        else               Cf32[idx] += v;
      }
    }
  }
}

// ---------------- 128x128 m97-structure GEMM: projection; XCD panel swizzle ----------------
// swz=1 (requires gridDim.x==16, (gy%8)==0): o%8 = XCD; panels round-robin per XCD ->
// each W-panel's 16 m-blocks run on ONE XCD -> panel L2-resident there (T1, bijective).
__global__ __launch_bounds__(256) void gemm128_k(
    const u16* __restrict__ A, const u16* __restrict__ Wt, float* __restrict__ C,
    int N, int K, int lda, int ldw, int ldc, int swz)
{
  int bx, by;
  if (swz){
    int o = blockIdx.y * gridDim.x + blockIdx.x;
    int k = o & 7, j = o >> 3;
    bx = j & 15;
    by = k + 8 * (j >> 4);
  } else { bx = blockIdx.x; by = blockIdx.y; }
  int m0 = bx * 128;
  int n0 = by * 128;
  __shared__ __align__(16) u16 SM[2 * 128 * 64];
  u16* As = SM;
  u16* Ws = SM + 128 * 64;

  int tid = threadIdx.x, lane = tid & 63, wid = tid >> 6;
  int wr = wid >> 1, wc = wid & 1;
  int l8 = lane >> 3;
  int sl = (lane & 7) ^ l8;

  f32x4 acc[4][4];
  #pragma unroll
  for (int i = 0; i < 4; ++i)
    #pragma unroll
    for (int j = 0; j < 4; ++j) acc[i][j] = (f32x4){0.f, 0.f, 0.f, 0.f};

  for (int k0 = 0; k0 < K; k0 += 64){
    #pragma unroll
    for (int j = 0; j < 4; ++j){
      int c = wid * 4 + j;
      const u16* ga = A  + (size_t)(m0 + 8*c + l8) * lda + k0 + sl*8;
      const u16* gw = Wt + (size_t)(n0 + 8*c + l8) * ldw + k0 + sl*8;
      __builtin_amdgcn_global_load_lds((const __attribute__((address_space(1))) void*)ga,
          (__attribute__((address_space(3))) void*)(As + c*512), 16, 0, 0);
      __builtin_amdgcn_global_load_lds((const __attribute__((address_space(1))) void*)gw,
          (__attribute__((address_space(3))) void*)(Ws + c*512), 16, 0, 0);
    }
    __syncthreads();
    #pragma unroll
    for (int kk = 0; kk < 2; ++kk){
      int slot = kk*4 + (lane >> 4);
      bf16x8 av[4], bv[4];
      #pragma unroll
      for (int mi = 0; mi < 4; ++mi){
        int r = wr*64 + mi*16 + (lane & 15);
        av[mi] = *(const bf16x8*)(As + r*64 + ((slot ^ (r & 7)) << 3));
      }
      #pragma unroll
      for (int ni = 0; ni < 4; ++ni){
        int r = wc*64 + ni*16 + (lane & 15);
        bv[ni] = *(const bf16x8*)(Ws + r*64 + ((slot ^ (r & 7)) << 3));
      }
      #pragma unroll
      for (int mi = 0; mi < 4; ++mi)
        #pragma unroll
        for (int ni = 0; ni < 4; ++ni)
          acc[mi][ni] = __builtin_amdgcn_mfma_f32_16x16x32_bf16(av[mi], bv[ni], acc[mi][ni], 0, 0, 0);
    }
    __syncthreads();
  }

  float* flds = (float*)SM;
  #pragma unroll
  for (int hf = 0; hf < 2; ++hf){
    if (wr == hf){
      #pragma unroll
      for (int mi = 0; mi < 4; ++mi){
        int rb = mi*16 + ((lane >> 4) << 2);
        #pragma unroll
        for (int ni = 0; ni < 4; ++ni){
          int colL = wc*64 + ni*16 + (lane & 15);
          #pragma unroll
          for (int r = 0; r < 4; ++r)
            flds[(rb + r)*128 + colL] = acc[mi][ni][r];
        }
      }
    }
    __syncthreads();
    int c = tid & 127;
    int gc = n0 + c;
    if (gc < N){
      for (int rr = (tid >> 7); rr < 64; rr += 2)
        C[(size_t)(m0 + hf*64 + rr) * ldc + gc] = flds[rr*128 + c];
    }
    __syncthreads();
  }
}

extern "C" void kernel_launch(void* const* d_in, const int* in_sizes, int n_in,
                              void* d_out, int out_size, void* d_ws, size_t ws_size,
                              hipStream_t stream)
{
  (void)in_sizes; (void)n_in; (void)out_size; (void)ws_size;
  const int* ids = (const int*)d_in[0];
  const void* tok = d_in[1];  const void* pos = d_in[2];
  const void* ln1g = d_in[3]; const void* ln1b = d_in[4];
  const void* wq = d_in[5];   const void* bq = d_in[6];
  const void* wk = d_in[7];   const void* bk = d_in[8];
  const void* wv = d_in[9];   const void* bv = d_in[10];
  const void* wo = d_in[11];  const void* bo = d_in[12];
  const void* ln2g = d_in[13]; const void* ln2b = d_in[14];
  const void* w1 = d_in[15];  const void* b1 = d_in[16];
  const void* w2 = d_in[17];  const void* b2 = d_in[18];
  const void* lnfg = d_in[19]; const void* lnfb = d_in[20];
  const void* pw = d_in[21];

  char* ob = (char*)d_out;
  float* logitsF = (float*)ob;
  float* attnF   = (float*)(ob + 411705344);
  float* x    = (float*)(ob + 100663296);
  u16* qkv    = (u16*)(ob + 106954752);
  u16* ctx    = (u16*)(ob + 116391936);
  u16* ff     = (u16*)(ob + 119537664);
  u16* wT     = (u16*)(ob + 132120576);
  u16* biascat= (u16*)(ob + 188743680);
  float* stats= (float*)(ob + 188762112);
  const long LSTR = 7077888;
  char* wsp = (char*)d_ws;
  int* dflag = (int*)wsp;
  u16* h      = (u16*)(wsp + 256);
  u16* chunkT = (u16*)(wsp + 256 + 3145728);

  const int BT = B_ * T_;
  detect_k<<<1, 256, 0, stream>>>((const u16*)tok, dflag);
  bcat_k<<<L_, 256, 0, stream>>>(bq, bk, bv, biascat, dflag);
  {
    dim3 gDD(24, 24, L_), g1(96, 24, L_), g2(24, 96, L_);
    transpose_k<<<gDD, 256, 0, stream>>>(wq, wT,            D_, D_,  D_,  0, (long)D_*D_,  LSTR, dflag);
    transpose_k<<<gDD, 256, 0, stream>>>(wk, wT + 589824,   D_, D_,  D_,  0, (long)D_*D_,  LSTR, dflag);
    transpose_k<<<gDD, 256, 0, stream>>>(wv, wT + 2*589824, D_, D_,  D_,  0, (long)D_*D_,  LSTR, dflag);
    transpose_k<<<gDD, 256, 0, stream>>>(wo, wT + 3*589824, D_, D_,  D_,  0, (long)D_*D_,  LSTR, dflag);
    transpose_k<<<g1, 256, 0, stream>>>(w1, wT + 4*589824,  D_, FF_, FF_, 0, (long)D_*FF_, LSTR, dflag);
    transpose_k<<<g2, 256, 0, stream>>>(w2, wT + 4*589824 + 2359296, FF_, D_, D_, 0, (long)FF_*D_, LSTR, dflag);
  }
  embed_k<<<BT, 256, 0, stream>>>(ids, tok, pos, x, dflag);

  dim3 gQKV(36, 16);
  dim3 gFF1(48, 16);
  dim3 gD(12, 32);
  dim3 gA(16, B_*H_);

  for (int l = 0; l < L_; ++l){
    long oB = (long)l * D_, oB1 = (long)l * FF_;
    u16* wl  = wT + (size_t)l * LSTR;
    u16* woT = wl + 3*589824;
    u16* w1T = wl + 4*589824;
    u16* w2T = w1T + 2359296;
    ln_k<<<BT, 256, 0, stream>>>(x, ln1g, ln1b, oB, h, dflag);
    gemmw_k<0><<<gQKV, 256, 0, stream>>>(h, wl, biascat, (long)l*3*D_, qkv, nullptr, nullptr,
        3*D_, D_, D_, D_, 3*D_);
    fattn_k<<<gA, 256, 0, stream>>>(qkv, ctx, stats);
    if (l == L_-1)
      probs_k<<<gA, 256, 0, stream>>>(qkv, stats, attnF);
    gemm_k<2><<<gD, 256, 0, stream>>>(ctx, woT, bo, oB, nullptr, x, dflag,
        D_, D_, D_, D_, D_);
    ln_k<<<BT, 256, 0, stream>>>(x, ln2g, ln2b, oB, h, dflag);
    gemmw_k<1><<<gFF1, 256, 0, stream>>>(h, w1T, b1, oB1, ff, nullptr, dflag,
        FF_, D_, D_, D_, FF_);
    gemm_k<2><<<gD, 256, 0, stream>>>(ff, w2T, b2, oB, nullptr, x, dflag,
        D_, FF_, FF_, FF_, D_);
  }
  ln_k<<<BT, 256, 0, stream>>>(x, lnfg, lnfb, 0, h, dflag);
  {
    // CHUNK chosen so the 4 main chunks have ny=96 (%8==0) for the bijective XCD swizzle
    const int CHUNK = 12288;   // 96 * 128
    int done = 0;
    while (done < V_){
      int cols = V_ - done; if (cols > CHUNK) cols = CHUNK;
      dim3 gt((cols + 31) / 32, 24);
      transpose_k<<<gt, 256, 0, stream>>>(pw, chunkT, D_, cols, V_, (long)done, 0, 0, dflag);
      int ny = (cols + 127) / 128;
      dim3 gp(16, ny);
      int swz = (ny % 8 == 0) ? 1 : 0;
      gemm128_k<<<gp, 256, 0, stream>>>(h, chunkT, logitsF + done, cols, D_, D_, D_, V_, swz);
      done += cols;
    }
  }
}

// Round 18
// 1099.163 us; speedup vs baseline: 1.0414x; 1.0134x over previous
//
#include <hip/hip_runtime.h>

typedef unsigned short u16;
typedef unsigned int u32;
typedef __bf16 bf16x8 __attribute__((ext_vector_type(8)));
typedef float f32x4 __attribute__((ext_vector_type(4)));

#define L_ 4
#define D_ 768
#define T_ 1024
#define B_ 2
#define H_ 12
#define DK_ 64
#define FF_ 3072
#define V_ 50257

__device__ __forceinline__ float bf2f(u16 u){ return __uint_as_float(((unsigned)u) << 16); }
__device__ __forceinline__ u16 f2bf(float f){
  unsigned x = __float_as_uint(f);
  return (u16)((x + 0x7fffu + ((x >> 16) & 1u)) >> 16);   // RNE
}

// ---- input dtype probe (HW-proven f32; kept as insurance) ----
__global__ __launch_bounds__(256) void detect_k(const u16* __restrict__ w, int* __restrict__ flag){
  __shared__ int s;
  if (threadIdx.x == 0) s = 0;
  __syncthreads();
  int bad = 0;
  for (int j = threadIdx.x; j < 4096; j += 256){
    int e = (w[j] >> 7) & 0xFF;
    if (e >= 0xC0) bad = 1;
  }
  if (bad) atomicOr(&s, 1);
  __syncthreads();
  if (threadIdx.x == 0) flag[0] = s;
}

__device__ __forceinline__ float rdin(const void* p, long i, bool wf){
  return wf ? ((const float*)p)[i] : bf2f(((const u16*)p)[i]);
}

// ---------------- embedding ----------------
__global__ __launch_bounds__(256) void embed_k(const int* __restrict__ ids,
    const void* __restrict__ tok, const void* __restrict__ pos, float* __restrict__ x,
    const int* __restrict__ dflag){
  bool wf = dflag[0] != 0;
  int row = blockIdx.x; int t = row & (T_-1);
  long id = ids[row];
  float* xr = x + (size_t)row * D_;
  for (int d = threadIdx.x; d < D_; d += 256)
    xr[d] = rdin(tok, id * (long)D_ + d, wf) + rdin(pos, (long)t * D_ + d, wf);
}

// ---------------- layernorm: f32 x -> bf16 h ----------------
__global__ __launch_bounds__(256) void ln_k(const float* __restrict__ x,
    const void* __restrict__ g, const void* __restrict__ bb, long goff, u16* __restrict__ out,
    const int* __restrict__ dflag){
  __shared__ float red[8];
  bool wf = dflag[0] != 0;
  int row = blockIdx.x, tid = threadIdx.x;
  const float* xr = x + (size_t)row * D_;
  float v[3]; float s = 0.f, s2 = 0.f;
  #pragma unroll
  for (int i = 0; i < 3; ++i){ float t = xr[tid + i*256]; v[i] = t; s += t; s2 += t*t; }
  #pragma unroll
  for (int o = 1; o < 64; o <<= 1){ s += __shfl_xor(s, o, 64); s2 += __shfl_xor(s2, o, 64); }
  if ((tid & 63) == 0){ red[tid >> 6] = s; red[(tid >> 6) + 4] = s2; }
  __syncthreads();
  s  = red[0] + red[1] + red[2] + red[3];
  s2 = red[4] + red[5] + red[6] + red[7];
  float mean = s * (1.f / D_);
  float var  = s2 * (1.f / D_) - mean * mean;
  float rstd = rsqrtf(var + 1e-5f);
  u16* orow = out + (size_t)row * D_;
  #pragma unroll
  for (int i = 0; i < 3; ++i){
    int d = tid + i*256;
    orow[d] = f2bf((v[i] - mean) * rstd * rdin(g, goff + d, wf) + rdin(bb, goff + d, wf));
  }
}

// ---------------- fused flash attention (ALL layers); emits per-row (m,l) stats ----------------
__global__ __launch_bounds__(256) void fattn_k(const u16* __restrict__ qkv, u16* __restrict__ ctx,
                                               float* __restrict__ stats){
  __shared__ __align__(16) u16 Qs[64][72];   // later reused as P
  __shared__ __align__(16) u16 Ks[64][72];
  __shared__ __align__(16) u16 Vt[64][72];   // V transposed: [d][k]
  int qb = 15 - blockIdx.x;
  int bh = blockIdx.y;
  int b = bh / H_, h = bh % H_;
  const u16* base = qkv + (size_t)b * T_ * 3*D_;
  int qoff = h*64, koff = D_ + h*64, voff = 2*D_ + h*64;
  int tid = threadIdx.x, lane = tid & 63, w = tid >> 6;
  int sr = tid >> 3, sc = (tid & 7) << 3;
  int l15 = lane & 15, lg = lane >> 4;

  {
    const u16* gq = base + (size_t)(qb*64 + sr) * 3*D_ + qoff + sc;
    *(int4*)(&Qs[sr][sc])      = *(const int4*)gq;
    *(int4*)(&Qs[sr + 32][sc]) = *(const int4*)(gq + (size_t)32 * 3*D_);
  }
  __syncthreads();
  bf16x8 aq[2];
  #pragma unroll
  for (int kk = 0; kk < 2; ++kk)
    aq[kk] = *(const bf16x8*)(&Qs[w*16 + l15][kk*32 + lg*8]);

  f32x4 oacc[4];
  #pragma unroll
  for (int i = 0; i < 4; ++i) oacc[i] = (f32x4){0.f,0.f,0.f,0.f};
  float m_run[4] = {-1e30f,-1e30f,-1e30f,-1e30f};
  float l_run[4] = {0.f,0.f,0.f,0.f};

  for (int kb = 0; kb <= qb; ++kb){
    __syncthreads();
    {
      const u16* gk = base + (size_t)(kb*64 + sr) * 3*D_ + koff + sc;
      *(int4*)(&Ks[sr][sc])      = *(const int4*)gk;
      *(int4*)(&Ks[sr + 32][sc]) = *(const int4*)(gk + (size_t)32 * 3*D_);
      const u16* gv = base + (size_t)(kb*64 + sr) * 3*D_ + voff + sc;
      u16 tmp[8];
      *(int4*)tmp = *(const int4*)gv;
      #pragma unroll
      for (int j = 0; j < 8; ++j) Vt[sc + j][sr] = tmp[j];
      *(int4*)tmp = *(const int4*)(gv + (size_t)32 * 3*D_);
      #pragma unroll
      for (int j = 0; j < 8; ++j) Vt[sc + j][sr + 32] = tmp[j];
    }
    __syncthreads();
    f32x4 sacc[4];
    #pragma unroll
    for (int i = 0; i < 4; ++i) sacc[i] = (f32x4){0.f,0.f,0.f,0.f};
    #pragma unroll
    for (int kk = 0; kk < 2; ++kk){
      #pragma unroll
      for (int ni = 0; ni < 4; ++ni){
        bf16x8 bk = *(const bf16x8*)(&Ks[ni*16 + l15][kk*32 + lg*8]);
        sacc[ni] = __builtin_amdgcn_mfma_f32_16x16x32_bf16(aq[kk], bk, sacc[ni], 0, 0, 0);
      }
    }
    #pragma unroll
    for (int ni = 0; ni < 4; ++ni)
      #pragma unroll
      for (int r = 0; r < 4; ++r){
        float s = sacc[ni][r] * 0.125f;
        if (kb == qb){
          int rowL = w*16 + lg*4 + r, colL = ni*16 + l15;
          if (colL > rowL) s = -1e30f;
        }
        sacc[ni][r] = s;
      }
    float mx[4], ps[4];
    #pragma unroll
    for (int r = 0; r < 4; ++r){
      float m = fmaxf(fmaxf(sacc[0][r], sacc[1][r]), fmaxf(sacc[2][r], sacc[3][r]));
      #pragma unroll
      for (int o = 1; o < 16; o <<= 1) m = fmaxf(m, __shfl_xor(m, o, 64));
      mx[r] = m;
    }
    #pragma unroll
    for (int r = 0; r < 4; ++r){
      float m_new = fmaxf(m_run[r], mx[r]);
      float alpha = expf(m_run[r] - m_new);
      float sum = 0.f;
      #pragma unroll
      for (int ni = 0; ni < 4; ++ni){
        float p = expf(sacc[ni][r] - m_new);
        sacc[ni][r] = p;
        sum += p;
      }
      #pragma unroll
      for (int o = 1; o < 16; o <<= 1) sum += __shfl_xor(sum, o, 64);
      m_run[r] = m_new;
      l_run[r] = l_run[r] * alpha + sum;
      ps[r] = alpha;
    }
    #pragma unroll
    for (int ni = 0; ni < 4; ++ni)
      #pragma unroll
      for (int r = 0; r < 4; ++r)
        oacc[ni][r] *= ps[r];
    #pragma unroll
    for (int ni = 0; ni < 4; ++ni)
      #pragma unroll
      for (int r = 0; r < 4; ++r)
        Qs[w*16 + lg*4 + r][ni*16 + l15] = f2bf(sacc[ni][r]);
    #pragma unroll
    for (int kk = 0; kk < 2; ++kk){
      bf16x8 ap = *(const bf16x8*)(&Qs[w*16 + l15][kk*32 + lg*8]);
      #pragma unroll
      for (int ni = 0; ni < 4; ++ni){
        bf16x8 bv = *(const bf16x8*)(&Vt[ni*16 + l15][kk*32 + lg*8]);
        oacc[ni] = __builtin_amdgcn_mfma_f32_16x16x32_bf16(ap, bv, oacc[ni], 0, 0, 0);
      }
    }
  }
  float inv[4];
  #pragma unroll
  for (int r = 0; r < 4; ++r) inv[r] = 1.f / l_run[r];
  #pragma unroll
  for (int ni = 0; ni < 4; ++ni){
    int col = h*64 + ni*16 + l15;
    #pragma unroll
    for (int r = 0; r < 4; ++r){
      int row = b*T_ + qb*64 + w*16 + lg*4 + r;
      ctx[(size_t)row * D_ + col] = f2bf(oacc[ni][r] * inv[r]);
    }
  }
  if (l15 == 0){
    float2* st = (float2*)stats;
    #pragma unroll
    for (int r = 0; r < 4; ++r){
      int row = qb*64 + w*16 + lg*4 + r;
      st[(size_t)bh * T_ + row] = make_float2(m_run[r], l_run[r]);
    }
  }
}

// ---------------- probs reconstruction (layer 3): attn = exp(QK^T/8 - m)/l, f32, full rows ----------------
__global__ __launch_bounds__(256) void probs_k(const u16* __restrict__ qkv,
    const float* __restrict__ stats, float* __restrict__ attnf){
  __shared__ __align__(16) u16 Qs[64][72];
  __shared__ __align__(16) u16 Ks[64][72];
  __shared__ float P[64][68];
  int qb = 15 - blockIdx.x;
  int bh = blockIdx.y;
  int b = bh / H_, h = bh % H_;
  const u16* base = qkv + (size_t)b * T_ * 3*D_;
  int qoff = h*64, koff = D_ + h*64;
  float* abase = attnf + (size_t)bh * T_ * T_;
  int tid = threadIdx.x, lane = tid & 63, w = tid >> 6;
  int sr = tid >> 3, sc = (tid & 7) << 3;
  int l15 = lane & 15, lg = lane >> 4;

  {
    const u16* gq = base + (size_t)(qb*64 + sr) * 3*D_ + qoff + sc;
    *(int4*)(&Qs[sr][sc])      = *(const int4*)gq;
    *(int4*)(&Qs[sr + 32][sc]) = *(const int4*)(gq + (size_t)32 * 3*D_);
  }
  __syncthreads();
  bf16x8 aq[2];
  #pragma unroll
  for (int kk = 0; kk < 2; ++kk)
    aq[kk] = *(const bf16x8*)(&Qs[w*16 + l15][kk*32 + lg*8]);
  float mrow[4], lirow[4];
  {
    const float2* st = (const float2*)stats;
    #pragma unroll
    for (int r = 0; r < 4; ++r){
      float2 s = st[(size_t)bh * T_ + qb*64 + w*16 + lg*4 + r];
      mrow[r] = s.x; lirow[r] = 1.f / s.y;
    }
  }

  for (int kb = 0; kb <= qb; ++kb){
    __syncthreads();
    {
      const u16* gk = base + (size_t)(kb*64 + sr) * 3*D_ + koff + sc;
      *(int4*)(&Ks[sr][sc])      = *(const int4*)gk;
      *(int4*)(&Ks[sr + 32][sc]) = *(const int4*)(gk + (size_t)32 * 3*D_);
    }
    __syncthreads();
    f32x4 sacc[4];
    #pragma unroll
    for (int i = 0; i < 4; ++i) sacc[i] = (f32x4){0.f,0.f,0.f,0.f};
    #pragma unroll
    for (int kk = 0; kk < 2; ++kk){
      #pragma unroll
      for (int ni = 0; ni < 4; ++ni){
        bf16x8 bk = *(const bf16x8*)(&Ks[ni*16 + l15][kk*32 + lg*8]);
        sacc[ni] = __builtin_amdgcn_mfma_f32_16x16x32_bf16(aq[kk], bk, sacc[ni], 0, 0, 0);
      }
    }
    #pragma unroll
    for (int ni = 0; ni < 4; ++ni)
      #pragma unroll
      for (int r = 0; r < 4; ++r){
        int rowL = w*16 + lg*4 + r, colL = ni*16 + l15;
        float p = expf(sacc[ni][r] * 0.125f - mrow[r]) * lirow[r];
        if (kb == qb && colL > rowL) p = 0.f;
        P[rowL][colL] = p;
      }
    __syncthreads();
    #pragma unroll
    for (int p4 = 0; p4 < 4; ++p4){
      int row = p4*16 + (tid >> 4);
      int c0 = tid & 15;
      float* dst = abase + (size_t)(qb*64 + row) * T_ + kb*64;
      #pragma unroll
      for (int j = 0; j < 4; ++j)
        dst[c0 + j*16] = P[row][c0 + j*16];
    }
  }
  for (int r = 0; r < 64; ++r){
    float* dst = abase + (size_t)(qb*64 + r) * T_;
    for (int k = (qb+1)*64 + tid; k < T_; k += 256) dst[k] = 0.f;
  }
}

// ---------------- transpose+convert (z-batched, 64Rx32C tile, vectorized writes) ----------------
// raw [R][ldin] window -> bf16 [C][R].  Requires R % 64 == 0 (all callers: 768/3072).
__global__ __launch_bounds__(256) void transpose_k(const void* __restrict__ in, u16* __restrict__ outp,
                                                   int R, int C, int ldin, long ielem,
                                                   long zin, long zout,
                                                   const int* __restrict__ dflag){
  __shared__ u16 tile[32][72];                 // [c][r], 8B-aligned rows (144 B)
  bool wf = dflag[0] != 0;
  long zi = ielem + (long)blockIdx.z * zin;
  u16* op = outp + (size_t)blockIdx.z * zout;
  int c0 = blockIdx.x * 32, r0 = blockIdx.y * 64;
  int tid = threadIdx.x;
  int cl = tid & 31, rl = tid >> 5;            // read: unit-stride cols per wave
  int c = c0 + cl;
  bool okc = (c < C);
  #pragma unroll
  for (int p = 0; p < 8; ++p){
    int r = r0 + p*8 + rl;
    tile[cl][p*8 + rl] = okc ? f2bf(rdin(in, zi + (size_t)r * ldin + c, wf)) : (u16)0;
  }
  __syncthreads();
  int cs = tid >> 4, rs = (tid & 15) * 4;      // write: 8B per thread, 128B per 16 threads
  #pragma unroll
  for (int p = 0; p < 2; ++p){
    int cc = p*16 + cs;
    int cg = c0 + cc;
    if (cg < C){
      uint2 v = *(const uint2*)(&tile[cc][rs]);
      *(uint2*)(op + (size_t)cg * R + r0 + rs) = v;
    }
  }
}

// ---------------- qkv bias concat -> bf16 [L][2304] ----------------
__global__ __launch_bounds__(256) void bcat_k(const void* __restrict__ bq, const void* __restrict__ bk,
    const void* __restrict__ bv, u16* __restrict__ outp, const int* __restrict__ dflag){
  bool wf = dflag[0] != 0;
  int l = blockIdx.x;
  for (int j = threadIdx.x; j < 3*D_; j += 256){
    float v;
    if (j < D_)        v = rdin(bq, (long)l*D_ + j, wf);
    else if (j < 2*D_) v = rdin(bk, (long)l*D_ + j - D_, wf);
    else               v = rdin(bv, (long)l*D_ + j - 2*D_, wf);
    outp[(size_t)l*3*D_ + j] = f2bf(v);
  }
}

// ---------------- 64-tile GEMM (wo, ff2): gload_lds + swizzle ----------------
template<int EPI>
__global__ __launch_bounds__(256) void gemm_k(
    const u16* __restrict__ A, const u16* __restrict__ W, const void* __restrict__ bias,
    long belem,
    u16* __restrict__ Cbf, float* __restrict__ Cf32, const int* __restrict__ dflag,
    int N, int K, int lda, int ldw, int ldc)
{
  int m0 = blockIdx.y * 64;
  int n0 = blockIdx.x * 64;
  const bool wf = dflag && (dflag[0] != 0);

  __shared__ __align__(16) u16 SMEM[8192];
  u16* As = SMEM;
  u16* Ws = SMEM + 4096;

  int tid = threadIdx.x;
  int lane = tid & 63, wid = tid >> 6;
  int wr = wid >> 1, wc = wid & 1;
  int l15 = lane & 15, lg = lane >> 4;
  int l8 = lane >> 3;
  int sl = (lane & 7) ^ l8;

  f32x4 acc[2][2];
  #pragma unroll
  for (int i = 0; i < 2; ++i)
    #pragma unroll
    for (int j = 0; j < 2; ++j) acc[i][j] = (f32x4){0.f, 0.f, 0.f, 0.f};

  for (int k0 = 0; k0 < K; k0 += 64){
    #pragma unroll
    for (int i = 0; i < 2; ++i){
      int rb = i*32 + wid*8;
      const u16* ga = A + (size_t)(m0 + rb + l8) * lda + k0 + sl*8;
      __builtin_amdgcn_global_load_lds((const __attribute__((address_space(1))) void*)ga,
          (__attribute__((address_space(3))) void*)(As + rb*64), 16, 0, 0);
      const u16* gw = W + (size_t)(n0 + rb + l8) * ldw + k0 + sl*8;
      __builtin_amdgcn_global_load_lds((const __attribute__((address_space(1))) void*)gw,
          (__attribute__((address_space(3))) void*)(Ws + rb*64), 16, 0, 0);
    }
    __syncthreads();
    #pragma unroll
    for (int kk = 0; kk < 2; ++kk){
      int slot = kk*4 + lg;
      bf16x8 af[2], bfr[2];
      #pragma unroll
      for (int mi = 0; mi < 2; ++mi){
        int r = wr*32 + mi*16 + l15;
        af[mi] = *(const bf16x8*)(As + r*64 + ((slot ^ (r & 7)) << 3));
      }
      #pragma unroll
      for (int ni = 0; ni < 2; ++ni){
        int r = wc*32 + ni*16 + l15;
        bfr[ni] = *(const bf16x8*)(Ws + r*64 + ((slot ^ (r & 7)) << 3));
      }
      #pragma unroll
      for (int mi = 0; mi < 2; ++mi)
        #pragma unroll
        for (int ni = 0; ni < 2; ++ni)
          acc[mi][ni] = __builtin_amdgcn_mfma_f32_16x16x32_bf16(af[mi], bfr[ni], acc[mi][ni], 0, 0, 0);
    }
    __syncthreads();
  }

  #pragma unroll
  for (int ni = 0; ni < 2; ++ni){
    int col = n0 + wc*32 + ni*16 + l15;
    float bvv = 0.f;
    if (bias) bvv = wf ? ((const float*)bias)[belem + col] : bf2f(((const u16*)bias)[belem + col]);
    #pragma unroll
    for (int mi = 0; mi < 2; ++mi){
      int rbase = m0 + wr*32 + mi*16 + (lg << 2);
      #pragma unroll
      for (int r = 0; r < 4; ++r){
        int row = rbase + r;
        float v = acc[mi][ni][r] + bvv;
        size_t idx = (size_t)row * ldc + col;
        if (EPI == 0)      Cbf[idx] = f2bf(v);
        else if (EPI == 1){ float gg = 0.5f * v * (1.f + erff(v * 0.70710678118654752f)); Cbf[idx] = f2bf(gg); }
        else               Cf32[idx] += v;
      }
    }
  }
}

// ---------------- 128(M)x64(N)-tile GEMM (qkv, ff1) ----------------
template<int EPI>
__global__ __launch_bounds__(256) void gemmw_k(
    const u16* __restrict__ A, const u16* __restrict__ W, const void* __restrict__ bias,
    long belem,
    u16* __restrict__ Cbf, float* __restrict__ Cf32, const int* __restrict__ dflag,
    int N, int K, int lda, int ldw, int ldc)
{
  int m0 = blockIdx.y * 128;
  int n0 = blockIdx.x * 64;
  const bool wf = dflag && (dflag[0] != 0);

  __shared__ __align__(16) u16 SMEM[12288];
  u16* As = SMEM;
  u16* Ws = SMEM + 8192;

  int tid = threadIdx.x;
  int lane = tid & 63, wid = tid >> 6;
  int l15 = lane & 15, lg = lane >> 4;
  int l8 = lane >> 3;
  int sl = (lane & 7) ^ l8;

  f32x4 acc[2][4];
  #pragma unroll
  for (int i = 0; i < 2; ++i)
    #pragma unroll
    for (int j = 0; j < 4; ++j) acc[i][j] = (f32x4){0.f, 0.f, 0.f, 0.f};

  for (int k0 = 0; k0 < K; k0 += 64){
    #pragma unroll
    for (int j = 0; j < 4; ++j){
      int rb = j*32 + wid*8;
      const u16* ga = A + (size_t)(m0 + rb + l8) * lda + k0 + sl*8;
      __builtin_amdgcn_global_load_lds((const __attribute__((address_space(1))) void*)ga,
          (__attribute__((address_space(3))) void*)(As + rb*64), 16, 0, 0);
    }
    #pragma unroll
    for (int i = 0; i < 2; ++i){
      int rb = i*32 + wid*8;
      const u16* gw = W + (size_t)(n0 + rb + l8) * ldw + k0 + sl*8;
      __builtin_amdgcn_global_load_lds((const __attribute__((address_space(1))) void*)gw,
          (__attribute__((address_space(3))) void*)(Ws + rb*64), 16, 0, 0);
    }
    __syncthreads();
    #pragma unroll
    for (int kk = 0; kk < 2; ++kk){
      int slot = kk*4 + lg;
      bf16x8 af[2], bfr[4];
      #pragma unroll
      for (int mi = 0; mi < 2; ++mi){
        int r = wid*32 + mi*16 + l15;
        af[mi] = *(const bf16x8*)(As + r*64 + ((slot ^ (r & 7)) << 3));
      }
      #pragma unroll
      for (int ni = 0; ni < 4; ++ni){
        int r = ni*16 + l15;
        bfr[ni] = *(const bf16x8*)(Ws + r*64 + ((slot ^ (r & 7)) << 3));
      }
      #pragma unroll
      for (int mi = 0; mi < 2; ++mi)
        #pragma unroll
        for (int ni = 0; ni < 4; ++ni)
          acc[mi][ni] = __builtin_amdgcn_mfma_f32_16x16x32_bf16(af[mi], bfr[ni], acc[mi][ni], 0, 0, 0);
    }
    __syncthreads();
  }

  #pragma unroll
  for (int ni = 0; ni < 4; ++ni){
    int col = n0 + ni*16 + l15;
    float bvv = 0.f;
    if (bias) bvv = wf ? ((const float*)bias)[belem + col] : bf2f(((const u16*)bias)[belem + col]);
    #pragma unroll
    for (int mi = 0; mi < 2; ++mi){
      int rbase = m0 + wid*32 + mi*16 + (lg << 2);
      #pragma unroll
      for (int r = 0; r < 4; ++r){
        int row = rbase + r;
        float v = acc[mi][ni][r] + bvv;
        size_t idx = (size_t)row * ldc + col;
        if (EPI == 0)      Cbf[idx] = f2bf(v);
        else if (EPI == 1){ float gg = 0.5f * v * (1.f + erff(v * 0.70710678118654752f)); Cbf[idx] = f2bf(gg); }
        else               Cf32[idx] += v;
      }
    }
  }
}

// ---------------- 128x128 m97-structure GEMM: projection; XCD panel swizzle ----------------
__global__ __launch_bounds__(256) void gemm128_k(
    const u16* __restrict__ A, const u16* __restrict__ Wt, float* __restrict__ C,
    int N, int K, int lda, int ldw, int ldc, int swz)
{
  int bx, by;
  if (swz){
    int o = blockIdx.y * gridDim.x + blockIdx.x;
    int k = o & 7, j = o >> 3;
    bx = j & 15;
    by = k + 8 * (j >> 4);
  } else { bx = blockIdx.x; by = blockIdx.y; }
  int m0 = bx * 128;
  int n0 = by * 128;
  __shared__ __align__(16) u16 SM[2 * 128 * 64];
  u16* As = SM;
  u16* Ws = SM + 128 * 64;

  int tid = threadIdx.x, lane = tid & 63, wid = tid >> 6;
  int wr = wid >> 1, wc = wid & 1;
  int l8 = lane >> 3;
  int sl = (lane & 7) ^ l8;

  f32x4 acc[4][4];
  #pragma unroll
  for (int i = 0; i < 4; ++i)
    #pragma unroll
    for (int j = 0; j < 4; ++j) acc[i][j] = (f32x4){0.f, 0.f, 0.f, 0.f};

  for (int k0 = 0; k0 < K; k0 += 64){
    #pragma unroll
    for (int j = 0; j < 4; ++j){
      int c = wid * 4 + j;
      const u16* ga = A  + (size_t)(m0 + 8*c + l8) * lda + k0 + sl*8;
      const u16* gw = Wt + (size_t)(n0 + 8*c + l8) * ldw + k0 + sl*8;
      __builtin_amdgcn_global_load_lds((const __attribute__((address_space(1))) void*)ga,
          (__attribute__((address_space(3))) void*)(As + c*512), 16, 0, 0);
      __builtin_amdgcn_global_load_lds((const __attribute__((address_space(1))) void*)gw,
          (__attribute__((address_space(3))) void*)(Ws + c*512), 16, 0, 0);
    }
    __syncthreads();
    #pragma unroll
    for (int kk = 0; kk < 2; ++kk){
      int slot = kk*4 + (lane >> 4);
      bf16x8 av[4], bv[4];
      #pragma unroll
      for (int mi = 0; mi < 4; ++mi){
        int r = wr*64 + mi*16 + (lane & 15);
        av[mi] = *(const bf16x8*)(As + r*64 + ((slot ^ (r & 7)) << 3));
      }
      #pragma unroll
      for (int ni = 0; ni < 4; ++ni){
        int r = wc*64 + ni*16 + (lane & 15);
        bv[ni] = *(const bf16x8*)(Ws + r*64 + ((slot ^ (r & 7)) << 3));
      }
      #pragma unroll
      for (int mi = 0; mi < 4; ++mi)
        #pragma unroll
        for (int ni = 0; ni < 4; ++ni)
          acc[mi][ni] = __builtin_amdgcn_mfma_f32_16x16x32_bf16(av[mi], bv[ni], acc[mi][ni], 0, 0, 0);
    }
    __syncthreads();
  }

  float* flds = (float*)SM;
  #pragma unroll
  for (int hf = 0; hf < 2; ++hf){
    if (wr == hf){
      #pragma unroll
      for (int mi = 0; mi < 4; ++mi){
        int rb = mi*16 + ((lane >> 4) << 2);
        #pragma unroll
        for (int ni = 0; ni < 4; ++ni){
          int colL = wc*64 + ni*16 + (lane & 15);
          #pragma unroll
          for (int r = 0; r < 4; ++r)
            flds[(rb + r)*128 + colL] = acc[mi][ni][r];
        }
      }
    }
    __syncthreads();
    int c = tid & 127;
    int gc = n0 + c;
    if (gc < N){
      for (int rr = (tid >> 7); rr < 64; rr += 2)
        C[(size_t)(m0 + hf*64 + rr) * ldc + gc] = flds[rr*128 + c];
    }
    __syncthreads();
  }
}

extern "C" void kernel_launch(void* const* d_in, const int* in_sizes, int n_in,
                              void* d_out, int out_size, void* d_ws, size_t ws_size,
                              hipStream_t stream)
{
  (void)in_sizes; (void)n_in; (void)out_size; (void)ws_size;
  const int* ids = (const int*)d_in[0];
  const void* tok = d_in[1];  const void* pos = d_in[2];
  const void* ln1g = d_in[3]; const void* ln1b = d_in[4];
  const void* wq = d_in[5];   const void* bq = d_in[6];
  const void* wk = d_in[7];   const void* bk = d_in[8];
  const void* wv = d_in[9];   const void* bv = d_in[10];
  const void* wo = d_in[11];  const void* bo = d_in[12];
  const void* ln2g = d_in[13]; const void* ln2b = d_in[14];
  const void* w1 = d_in[15];  const void* b1 = d_in[16];
  const void* w2 = d_in[17];  const void* b2 = d_in[18];
  const void* lnfg = d_in[19]; const void* lnfb = d_in[20];
  const void* pw = d_in[21];

  char* ob = (char*)d_out;
  float* logitsF = (float*)ob;
  float* attnF   = (float*)(ob + 411705344);
  float* x    = (float*)(ob + 100663296);
  u16* qkv    = (u16*)(ob + 106954752);
  u16* ctx    = (u16*)(ob + 116391936);
  u16* ff     = (u16*)(ob + 119537664);
  u16* wT     = (u16*)(ob + 132120576);
  u16* biascat= (u16*)(ob + 188743680);
  float* stats= (float*)(ob + 188762112);
  const long LSTR = 7077888;
  char* wsp = (char*)d_ws;
  int* dflag = (int*)wsp;
  u16* h      = (u16*)(wsp + 256);
  u16* chunkT = (u16*)(wsp + 256 + 3145728);     // up to 25.2 MB; total 28.3 MB < proven >=34.6 MB

  const int BT = B_ * T_;
  detect_k<<<1, 256, 0, stream>>>((const u16*)tok, dflag);
  bcat_k<<<L_, 256, 0, stream>>>(bq, bk, bv, biascat, dflag);
  {
    dim3 gDD(24, 12, L_), g1(96, 12, L_), g2(24, 48, L_);
    transpose_k<<<gDD, 256, 0, stream>>>(wq, wT,            D_, D_,  D_,  0, (long)D_*D_,  LSTR, dflag);
    transpose_k<<<gDD, 256, 0, stream>>>(wk, wT + 589824,   D_, D_,  D_,  0, (long)D_*D_,  LSTR, dflag);
    transpose_k<<<gDD, 256, 0, stream>>>(wv, wT + 2*589824, D_, D_,  D_,  0, (long)D_*D_,  LSTR, dflag);
    transpose_k<<<gDD, 256, 0, stream>>>(wo, wT + 3*589824, D_, D_,  D_,  0, (long)D_*D_,  LSTR, dflag);
    transpose_k<<<g1, 256, 0, stream>>>(w1, wT + 4*589824,  D_, FF_, FF_, 0, (long)D_*FF_, LSTR, dflag);
    transpose_k<<<g2, 256, 0, stream>>>(w2, wT + 4*589824 + 2359296, FF_, D_, D_, 0, (long)FF_*D_, LSTR, dflag);
  }
  embed_k<<<BT, 256, 0, stream>>>(ids, tok, pos, x, dflag);

  dim3 gQKV(36, 16);
  dim3 gFF1(48, 16);
  dim3 gD(12, 32);
  dim3 gA(16, B_*H_);

  for (int l = 0; l < L_; ++l){
    long oB = (long)l * D_, oB1 = (long)l * FF_;
    u16* wl  = wT + (size_t)l * LSTR;
    u16* woT = wl + 3*589824;
    u16* w1T = wl + 4*589824;
    u16* w2T = w1T + 2359296;
    ln_k<<<BT, 256, 0, stream>>>(x, ln1g, ln1b, oB, h, dflag);
    gemmw_k<0><<<gQKV, 256, 0, stream>>>(h, wl, biascat, (long)l*3*D_, qkv, nullptr, nullptr,
        3*D_, D_, D_, D_, 3*D_);
    fattn_k<<<gA, 256, 0, stream>>>(qkv, ctx, stats);
    if (l == L_-1)
      probs_k<<<gA, 256, 0, stream>>>(qkv, stats, attnF);
    gemm_k<2><<<gD, 256, 0, stream>>>(ctx, woT, bo, oB, nullptr, x, dflag,
        D_, D_, D_, D_, D_);
    ln_k<<<BT, 256, 0, stream>>>(x, ln2g, ln2b, oB, h, dflag);
    gemmw_k<1><<<gFF1, 256, 0, stream>>>(h, w1T, b1, oB1, ff, nullptr, dflag,
        FF_, D_, D_, D_, FF_);
    gemm_k<2><<<gD, 256, 0, stream>>>(ff, w2T, b2, oB, nullptr, x, dflag,
        D_, FF_, FF_, FF_, D_);
  }
  ln_k<<<BT, 256, 0, stream>>>(x, lnfg, lnfb, 0, h, dflag);
  {
    // CHUNK: 3 full chunks of 16384 (ny=128, %8==0 -> bijective XCD swizzle) + tail
    const int CHUNK = 16384;   // 128 * 128
    int done = 0;
    while (done < V_){
      int cols = V_ - done; if (cols > CHUNK) cols = CHUNK;
      dim3 gt((cols + 31) / 32, 12);
      transpose_k<<<gt, 256, 0, stream>>>(pw, chunkT, D_, cols, V_, (long)done, 0, 0, dflag);
      int ny = (cols + 127) / 128;
      dim3 gp(16, ny);
      int swz = (ny % 8 == 0) ? 1 : 0;
      gemm128_k<<<gp, 256, 0, stream>>>(h, chunkT, logitsF + done, cols, D_, D_, D_, V_, swz);
      done += cols;
    }
  }
}

// Round 19
// 1077.901 us; speedup vs baseline: 1.0619x; 1.0197x over previous
//
#include <hip/hip_runtime.h>

typedef unsigned short u16;
typedef unsigned int u32;
typedef __bf16 bf16x8 __attribute__((ext_vector_type(8)));
typedef float f32x4 __attribute__((ext_vector_type(4)));

#define L_ 4
#define D_ 768
#define T_ 1024
#define B_ 2
#define H_ 12
#define DK_ 64
#define FF_ 3072
#define V_ 50257

__device__ __forceinline__ float bf2f(u16 u){ return __uint_as_float(((unsigned)u) << 16); }
__device__ __forceinline__ u16 f2bf(float f){
  unsigned x = __float_as_uint(f);
  return (u16)((x + 0x7fffu + ((x >> 16) & 1u)) >> 16);   // RNE
}

// ---- input dtype probe (HW-proven f32; kept as insurance) ----
__global__ __launch_bounds__(256) void detect_k(const u16* __restrict__ w, int* __restrict__ flag){
  __shared__ int s;
  if (threadIdx.x == 0) s = 0;
  __syncthreads();
  int bad = 0;
  for (int j = threadIdx.x; j < 4096; j += 256){
    int e = (w[j] >> 7) & 0xFF;
    if (e >= 0xC0) bad = 1;
  }
  if (bad) atomicOr(&s, 1);
  __syncthreads();
  if (threadIdx.x == 0) flag[0] = s;
}

__device__ __forceinline__ float rdin(const void* p, long i, bool wf){
  return wf ? ((const float*)p)[i] : bf2f(((const u16*)p)[i]);
}

// ---------------- embedding ----------------
__global__ __launch_bounds__(256) void embed_k(const int* __restrict__ ids,
    const void* __restrict__ tok, const void* __restrict__ pos, float* __restrict__ x,
    const int* __restrict__ dflag){
  bool wf = dflag[0] != 0;
  int row = blockIdx.x; int t = row & (T_-1);
  long id = ids[row];
  float* xr = x + (size_t)row * D_;
  for (int d = threadIdx.x; d < D_; d += 256)
    xr[d] = rdin(tok, id * (long)D_ + d, wf) + rdin(pos, (long)t * D_ + d, wf);
}

// ---------------- layernorm: f32 x -> bf16 h ----------------
__global__ __launch_bounds__(256) void ln_k(const float* __restrict__ x,
    const void* __restrict__ g, const void* __restrict__ bb, long goff, u16* __restrict__ out,
    const int* __restrict__ dflag){
  __shared__ float red[8];
  bool wf = dflag[0] != 0;
  int row = blockIdx.x, tid = threadIdx.x;
  const float* xr = x + (size_t)row * D_;
  float v[3]; float s = 0.f, s2 = 0.f;
  #pragma unroll
  for (int i = 0; i < 3; ++i){ float t = xr[tid + i*256]; v[i] = t; s += t; s2 += t*t; }
  #pragma unroll
  for (int o = 1; o < 64; o <<= 1){ s += __shfl_xor(s, o, 64); s2 += __shfl_xor(s2, o, 64); }
  if ((tid & 63) == 0){ red[tid >> 6] = s; red[(tid >> 6) + 4] = s2; }
  __syncthreads();
  s  = red[0] + red[1] + red[2] + red[3];
  s2 = red[4] + red[5] + red[6] + red[7];
  float mean = s * (1.f / D_);
  float var  = s2 * (1.f / D_) - mean * mean;
  float rstd = rsqrtf(var + 1e-5f);
  u16* orow = out + (size_t)row * D_;
  #pragma unroll
  for (int i = 0; i < 3; ++i){
    int d = tid + i*256;
    orow[d] = f2bf((v[i] - mean) * rstd * rdin(g, goff + d, wf) + rdin(bb, goff + d, wf));
  }
}

// ---------------- fused flash attention (ALL layers); emits per-row (m,l) stats ----------------
__global__ __launch_bounds__(256) void fattn_k(const u16* __restrict__ qkv, u16* __restrict__ ctx,
                                               float* __restrict__ stats){
  __shared__ __align__(16) u16 Qs[64][72];   // later reused as P
  __shared__ __align__(16) u16 Ks[64][72];
  __shared__ __align__(16) u16 Vt[64][72];   // V transposed: [d][k]
  int qb = 15 - blockIdx.x;
  int bh = blockIdx.y;
  int b = bh / H_, h = bh % H_;
  const u16* base = qkv + (size_t)b * T_ * 3*D_;
  int qoff = h*64, koff = D_ + h*64, voff = 2*D_ + h*64;
  int tid = threadIdx.x, lane = tid & 63, w = tid >> 6;
  int sr = tid >> 3, sc = (tid & 7) << 3;
  int l15 = lane & 15, lg = lane >> 4;

  {
    const u16* gq = base + (size_t)(qb*64 + sr) * 3*D_ + qoff + sc;
    *(int4*)(&Qs[sr][sc])      = *(const int4*)gq;
    *(int4*)(&Qs[sr + 32][sc]) = *(const int4*)(gq + (size_t)32 * 3*D_);
  }
  __syncthreads();
  bf16x8 aq[2];
  #pragma unroll
  for (int kk = 0; kk < 2; ++kk)
    aq[kk] = *(const bf16x8*)(&Qs[w*16 + l15][kk*32 + lg*8]);

  f32x4 oacc[4];
  #pragma unroll
  for (int i = 0; i < 4; ++i) oacc[i] = (f32x4){0.f,0.f,0.f,0.f};
  float m_run[4] = {-1e30f,-1e30f,-1e30f,-1e30f};
  float l_run[4] = {0.f,0.f,0.f,0.f};

  for (int kb = 0; kb <= qb; ++kb){
    __syncthreads();
    {
      const u16* gk = base + (size_t)(kb*64 + sr) * 3*D_ + koff + sc;
      *(int4*)(&Ks[sr][sc])      = *(const int4*)gk;
      *(int4*)(&Ks[sr + 32][sc]) = *(const int4*)(gk + (size_t)32 * 3*D_);
      const u16* gv = base + (size_t)(kb*64 + sr) * 3*D_ + voff + sc;
      u16 tmp[8];
      *(int4*)tmp = *(const int4*)gv;
      #pragma unroll
      for (int j = 0; j < 8; ++j) Vt[sc + j][sr] = tmp[j];
      *(int4*)tmp = *(const int4*)(gv + (size_t)32 * 3*D_);
      #pragma unroll
      for (int j = 0; j < 8; ++j) Vt[sc + j][sr + 32] = tmp[j];
    }
    __syncthreads();
    f32x4 sacc[4];
    #pragma unroll
    for (int i = 0; i < 4; ++i) sacc[i] = (f32x4){0.f,0.f,0.f,0.f};
    __builtin_amdgcn_s_setprio(1);
    #pragma unroll
    for (int kk = 0; kk < 2; ++kk){
      #pragma unroll
      for (int ni = 0; ni < 4; ++ni){
        bf16x8 bk = *(const bf16x8*)(&Ks[ni*16 + l15][kk*32 + lg*8]);
        sacc[ni] = __builtin_amdgcn_mfma_f32_16x16x32_bf16(aq[kk], bk, sacc[ni], 0, 0, 0);
      }
    }
    __builtin_amdgcn_s_setprio(0);
    #pragma unroll
    for (int ni = 0; ni < 4; ++ni)
      #pragma unroll
      for (int r = 0; r < 4; ++r){
        float s = sacc[ni][r] * 0.125f;
        if (kb == qb){
          int rowL = w*16 + lg*4 + r, colL = ni*16 + l15;
          if (colL > rowL) s = -1e30f;
        }
        sacc[ni][r] = s;
      }
    float mx[4], ps[4];
    #pragma unroll
    for (int r = 0; r < 4; ++r){
      float m = fmaxf(fmaxf(sacc[0][r], sacc[1][r]), fmaxf(sacc[2][r], sacc[3][r]));
      #pragma unroll
      for (int o = 1; o < 16; o <<= 1) m = fmaxf(m, __shfl_xor(m, o, 64));
      mx[r] = m;
    }
    #pragma unroll
    for (int r = 0; r < 4; ++r){
      float m_new = fmaxf(m_run[r], mx[r]);
      float alpha = expf(m_run[r] - m_new);
      float sum = 0.f;
      #pragma unroll
      for (int ni = 0; ni < 4; ++ni){
        float p = expf(sacc[ni][r] - m_new);
        sacc[ni][r] = p;
        sum += p;
      }
      #pragma unroll
      for (int o = 1; o < 16; o <<= 1) sum += __shfl_xor(sum, o, 64);
      m_run[r] = m_new;
      l_run[r] = l_run[r] * alpha + sum;
      ps[r] = alpha;
    }
    #pragma unroll
    for (int ni = 0; ni < 4; ++ni)
      #pragma unroll
      for (int r = 0; r < 4; ++r)
        oacc[ni][r] *= ps[r];
    #pragma unroll
    for (int ni = 0; ni < 4; ++ni)
      #pragma unroll
      for (int r = 0; r < 4; ++r)
        Qs[w*16 + lg*4 + r][ni*16 + l15] = f2bf(sacc[ni][r]);
    __builtin_amdgcn_s_setprio(1);
    #pragma unroll
    for (int kk = 0; kk < 2; ++kk){
      bf16x8 ap = *(const bf16x8*)(&Qs[w*16 + l15][kk*32 + lg*8]);
      #pragma unroll
      for (int ni = 0; ni < 4; ++ni){
        bf16x8 bv = *(const bf16x8*)(&Vt[ni*16 + l15][kk*32 + lg*8]);
        oacc[ni] = __builtin_amdgcn_mfma_f32_16x16x32_bf16(ap, bv, oacc[ni], 0, 0, 0);
      }
    }
    __builtin_amdgcn_s_setprio(0);
  }
  float inv[4];
  #pragma unroll
  for (int r = 0; r < 4; ++r) inv[r] = 1.f / l_run[r];
  #pragma unroll
  for (int ni = 0; ni < 4; ++ni){
    int col = h*64 + ni*16 + l15;
    #pragma unroll
    for (int r = 0; r < 4; ++r){
      int row = b*T_ + qb*64 + w*16 + lg*4 + r;
      ctx[(size_t)row * D_ + col] = f2bf(oacc[ni][r] * inv[r]);
    }
  }
  if (l15 == 0){
    float2* st = (float2*)stats;
    #pragma unroll
    for (int r = 0; r < 4; ++r){
      int row = qb*64 + w*16 + lg*4 + r;
      st[(size_t)bh * T_ + row] = make_float2(m_run[r], l_run[r]);
    }
  }
}

// ---------------- probs reconstruction (layer 3): attn = exp(QK^T/8 - m)/l, f32, full rows ----------------
__global__ __launch_bounds__(256) void probs_k(const u16* __restrict__ qkv,
    const float* __restrict__ stats, float* __restrict__ attnf){
  __shared__ __align__(16) u16 Qs[64][72];
  __shared__ __align__(16) u16 Ks[64][72];
  __shared__ float P[64][68];
  int qb = 15 - blockIdx.x;
  int bh = blockIdx.y;
  int b = bh / H_, h = bh % H_;
  const u16* base = qkv + (size_t)b * T_ * 3*D_;
  int qoff = h*64, koff = D_ + h*64;
  float* abase = attnf + (size_t)bh * T_ * T_;
  int tid = threadIdx.x, lane = tid & 63, w = tid >> 6;
  int sr = tid >> 3, sc = (tid & 7) << 3;
  int l15 = lane & 15, lg = lane >> 4;

  {
    const u16* gq = base + (size_t)(qb*64 + sr) * 3*D_ + qoff + sc;
    *(int4*)(&Qs[sr][sc])      = *(const int4*)gq;
    *(int4*)(&Qs[sr + 32][sc]) = *(const int4*)(gq + (size_t)32 * 3*D_);
  }
  __syncthreads();
  bf16x8 aq[2];
  #pragma unroll
  for (int kk = 0; kk < 2; ++kk)
    aq[kk] = *(const bf16x8*)(&Qs[w*16 + l15][kk*32 + lg*8]);
  float mrow[4], lirow[4];
  {
    const float2* st = (const float2*)stats;
    #pragma unroll
    for (int r = 0; r < 4; ++r){
      float2 s = st[(size_t)bh * T_ + qb*64 + w*16 + lg*4 + r];
      mrow[r] = s.x; lirow[r] = 1.f / s.y;
    }
  }

  for (int kb = 0; kb <= qb; ++kb){
    __syncthreads();
    {
      const u16* gk = base + (size_t)(kb*64 + sr) * 3*D_ + koff + sc;
      *(int4*)(&Ks[sr][sc])      = *(const int4*)gk;
      *(int4*)(&Ks[sr + 32][sc]) = *(const int4*)(gk + (size_t)32 * 3*D_);
    }
    __syncthreads();
    f32x4 sacc[4];
    #pragma unroll
    for (int i = 0; i < 4; ++i) sacc[i] = (f32x4){0.f,0.f,0.f,0.f};
    #pragma unroll
    for (int kk = 0; kk < 2; ++kk){
      #pragma unroll
      for (int ni = 0; ni < 4; ++ni){
        bf16x8 bk = *(const bf16x8*)(&Ks[ni*16 + l15][kk*32 + lg*8]);
        sacc[ni] = __builtin_amdgcn_mfma_f32_16x16x32_bf16(aq[kk], bk, sacc[ni], 0, 0, 0);
      }
    }
    #pragma unroll
    for (int ni = 0; ni < 4; ++ni)
      #pragma unroll
      for (int r = 0; r < 4; ++r){
        int rowL = w*16 + lg*4 + r, colL = ni*16 + l15;
        float p = expf(sacc[ni][r] * 0.125f - mrow[r]) * lirow[r];
        if (kb == qb && colL > rowL) p = 0.f;
        P[rowL][colL] = p;
      }
    __syncthreads();
    #pragma unroll
    for (int p4 = 0; p4 < 4; ++p4){
      int row = p4*16 + (tid >> 4);
      int c0 = tid & 15;
      float* dst = abase + (size_t)(qb*64 + row) * T_ + kb*64;
      #pragma unroll
      for (int j = 0; j < 4; ++j)
        dst[c0 + j*16] = P[row][c0 + j*16];
    }
  }
  for (int r = 0; r < 64; ++r){
    float* dst = abase + (size_t)(qb*64 + r) * T_;
    for (int k = (qb+1)*64 + tid; k < T_; k += 256) dst[k] = 0.f;
  }
}

// ---------------- transpose+convert (z-batched, 64Rx32C tile, vectorized writes) ----------------
__global__ __launch_bounds__(256) void transpose_k(const void* __restrict__ in, u16* __restrict__ outp,
                                                   int R, int C, int ldin, long ielem,
                                                   long zin, long zout,
                                                   const int* __restrict__ dflag){
  __shared__ u16 tile[32][72];
  bool wf = dflag[0] != 0;
  long zi = ielem + (long)blockIdx.z * zin;
  u16* op = outp + (size_t)blockIdx.z * zout;
  int c0 = blockIdx.x * 32, r0 = blockIdx.y * 64;
  int tid = threadIdx.x;
  int cl = tid & 31, rl = tid >> 5;
  int c = c0 + cl;
  bool okc = (c < C);
  #pragma unroll
  for (int p = 0; p < 8; ++p){
    int r = r0 + p*8 + rl;
    tile[cl][p*8 + rl] = okc ? f2bf(rdin(in, zi + (size_t)r * ldin + c, wf)) : (u16)0;
  }
  __syncthreads();
  int cs = tid >> 4, rs = (tid & 15) * 4;
  #pragma unroll
  for (int p = 0; p < 2; ++p){
    int cc = p*16 + cs;
    int cg = c0 + cc;
    if (cg < C){
      uint2 v = *(const uint2*)(&tile[cc][rs]);
      *(uint2*)(op + (size_t)cg * R + r0 + rs) = v;
    }
  }
}

// ---------------- qkv bias concat -> bf16 [L][2304] ----------------
__global__ __launch_bounds__(256) void bcat_k(const void* __restrict__ bq, const void* __restrict__ bk,
    const void* __restrict__ bv, u16* __restrict__ outp, const int* __restrict__ dflag){
  bool wf = dflag[0] != 0;
  int l = blockIdx.x;
  for (int j = threadIdx.x; j < 3*D_; j += 256){
    float v;
    if (j < D_)        v = rdin(bq, (long)l*D_ + j, wf);
    else if (j < 2*D_) v = rdin(bk, (long)l*D_ + j - D_, wf);
    else               v = rdin(bv, (long)l*D_ + j - 2*D_, wf);
    outp[(size_t)l*3*D_ + j] = f2bf(v);
  }
}

// ---------------- 64-tile GEMM (wo, ff2): split-K over blockIdx.z; atomic f32 += ----------------
__global__ __launch_bounds__(256) void gemm_k(
    const u16* __restrict__ A, const u16* __restrict__ W, const void* __restrict__ bias,
    long belem,
    float* __restrict__ Cf32, const int* __restrict__ dflag,
    int N, int K, int lda, int ldw, int ldc)
{
  int m0 = blockIdx.y * 64;
  int n0 = blockIdx.x * 64;
  const bool wf = dflag && (dflag[0] != 0);
  int Ks = K / gridDim.z;
  int koff = blockIdx.z * Ks;
  bool dob = (blockIdx.z == 0);

  __shared__ __align__(16) u16 SMEM[8192];
  u16* As = SMEM;
  u16* Ws = SMEM + 4096;

  int tid = threadIdx.x;
  int lane = tid & 63, wid = tid >> 6;
  int wr = wid >> 1, wc = wid & 1;
  int l15 = lane & 15, lg = lane >> 4;
  int l8 = lane >> 3;
  int sl = (lane & 7) ^ l8;

  f32x4 acc[2][2];
  #pragma unroll
  for (int i = 0; i < 2; ++i)
    #pragma unroll
    for (int j = 0; j < 2; ++j) acc[i][j] = (f32x4){0.f, 0.f, 0.f, 0.f};

  for (int k0 = koff; k0 < koff + Ks; k0 += 64){
    #pragma unroll
    for (int i = 0; i < 2; ++i){
      int rb = i*32 + wid*8;
      const u16* ga = A + (size_t)(m0 + rb + l8) * lda + k0 + sl*8;
      __builtin_amdgcn_global_load_lds((const __attribute__((address_space(1))) void*)ga,
          (__attribute__((address_space(3))) void*)(As + rb*64), 16, 0, 0);
      const u16* gw = W + (size_t)(n0 + rb + l8) * ldw + k0 + sl*8;
      __builtin_amdgcn_global_load_lds((const __attribute__((address_space(1))) void*)gw,
          (__attribute__((address_space(3))) void*)(Ws + rb*64), 16, 0, 0);
    }
    __syncthreads();
    #pragma unroll
    for (int kk = 0; kk < 2; ++kk){
      int slot = kk*4 + lg;
      bf16x8 af[2], bfr[2];
      #pragma unroll
      for (int mi = 0; mi < 2; ++mi){
        int r = wr*32 + mi*16 + l15;
        af[mi] = *(const bf16x8*)(As + r*64 + ((slot ^ (r & 7)) << 3));
      }
      #pragma unroll
      for (int ni = 0; ni < 2; ++ni){
        int r = wc*32 + ni*16 + l15;
        bfr[ni] = *(const bf16x8*)(Ws + r*64 + ((slot ^ (r & 7)) << 3));
      }
      #pragma unroll
      for (int mi = 0; mi < 2; ++mi)
        #pragma unroll
        for (int ni = 0; ni < 2; ++ni)
          acc[mi][ni] = __builtin_amdgcn_mfma_f32_16x16x32_bf16(af[mi], bfr[ni], acc[mi][ni], 0, 0, 0);
    }
    __syncthreads();
  }

  #pragma unroll
  for (int ni = 0; ni < 2; ++ni){
    int col = n0 + wc*32 + ni*16 + l15;
    float bvv = 0.f;
    if (dob && bias) bvv = wf ? ((const float*)bias)[belem + col] : bf2f(((const u16*)bias)[belem + col]);
    #pragma unroll
    for (int mi = 0; mi < 2; ++mi){
      int rbase = m0 + wr*32 + mi*16 + (lg << 2);
      #pragma unroll
      for (int r = 0; r < 4; ++r){
        int row = rbase + r;
        float v = acc[mi][ni][r] + bvv;
        atomicAdd(&Cf32[(size_t)row * ldc + col], v);
      }
    }
  }
}

// ---------------- 128(M)x64(N)-tile GEMM (qkv, ff1) ----------------
template<int EPI>
__global__ __launch_bounds__(256) void gemmw_k(
    const u16* __restrict__ A, const u16* __restrict__ W, const void* __restrict__ bias,
    long belem,
    u16* __restrict__ Cbf, float* __restrict__ Cf32, const int* __restrict__ dflag,
    int N, int K, int lda, int ldw, int ldc)
{
  int m0 = blockIdx.y * 128;
  int n0 = blockIdx.x * 64;
  const bool wf = dflag && (dflag[0] != 0);

  __shared__ __align__(16) u16 SMEM[12288];
  u16* As = SMEM;
  u16* Ws = SMEM + 8192;

  int tid = threadIdx.x;
  int lane = tid & 63, wid = tid >> 6;
  int l15 = lane & 15, lg = lane >> 4;
  int l8 = lane >> 3;
  int sl = (lane & 7) ^ l8;

  f32x4 acc[2][4];
  #pragma unroll
  for (int i = 0; i < 2; ++i)
    #pragma unroll
    for (int j = 0; j < 4; ++j) acc[i][j] = (f32x4){0.f, 0.f, 0.f, 0.f};

  for (int k0 = 0; k0 < K; k0 += 64){
    #pragma unroll
    for (int j = 0; j < 4; ++j){
      int rb = j*32 + wid*8;
      const u16* ga = A + (size_t)(m0 + rb + l8) * lda + k0 + sl*8;
      __builtin_amdgcn_global_load_lds((const __attribute__((address_space(1))) void*)ga,
          (__attribute__((address_space(3))) void*)(As + rb*64), 16, 0, 0);
    }
    #pragma unroll
    for (int i = 0; i < 2; ++i){
      int rb = i*32 + wid*8;
      const u16* gw = W + (size_t)(n0 + rb + l8) * ldw + k0 + sl*8;
      __builtin_amdgcn_global_load_lds((const __attribute__((address_space(1))) void*)gw,
          (__attribute__((address_space(3))) void*)(Ws + rb*64), 16, 0, 0);
    }
    __syncthreads();
    #pragma unroll
    for (int kk = 0; kk < 2; ++kk){
      int slot = kk*4 + lg;
      bf16x8 af[2], bfr[4];
      #pragma unroll
      for (int mi = 0; mi < 2; ++mi){
        int r = wid*32 + mi*16 + l15;
        af[mi] = *(const bf16x8*)(As + r*64 + ((slot ^ (r & 7)) << 3));
      }
      #pragma unroll
      for (int ni = 0; ni < 4; ++ni){
        int r = ni*16 + l15;
        bfr[ni] = *(const bf16x8*)(Ws + r*64 + ((slot ^ (r & 7)) << 3));
      }
      #pragma unroll
      for (int mi = 0; mi < 2; ++mi)
        #pragma unroll
        for (int ni = 0; ni < 4; ++ni)
          acc[mi][ni] = __builtin_amdgcn_mfma_f32_16x16x32_bf16(af[mi], bfr[ni], acc[mi][ni], 0, 0, 0);
    }
    __syncthreads();
  }

  #pragma unroll
  for (int ni = 0; ni < 4; ++ni){
    int col = n0 + ni*16 + l15;
    float bvv = 0.f;
    if (bias) bvv = wf ? ((const float*)bias)[belem + col] : bf2f(((const u16*)bias)[belem + col]);
    #pragma unroll
    for (int mi = 0; mi < 2; ++mi){
      int rbase = m0 + wid*32 + mi*16 + (lg << 2);
      #pragma unroll
      for (int r = 0; r < 4; ++r){
        int row = rbase + r;
        float v = acc[mi][ni][r] + bvv;
        size_t idx = (size_t)row * ldc + col;
        if (EPI == 0)      Cbf[idx] = f2bf(v);
        else if (EPI == 1){ float gg = 0.5f * v * (1.f + erff(v * 0.70710678118654752f)); Cbf[idx] = f2bf(gg); }
        else               Cf32[idx] += v;
      }
    }
  }
}

// ---------------- 128x128 m97-structure GEMM: projection; XCD panel swizzle ----------------
__global__ __launch_bounds__(256) void gemm128_k(
    const u16* __restrict__ A, const u16* __restrict__ Wt, float* __restrict__ C,
    int N, int K, int lda, int ldw, int ldc, int swz)
{
  int bx, by;
  if (swz){
    int o = blockIdx.y * gridDim.x + blockIdx.x;
    int k = o & 7, j = o >> 3;
    bx = j & 15;
    by = k + 8 * (j >> 4);
  } else { bx = blockIdx.x; by = blockIdx.y; }
  int m0 = bx * 128;
  int n0 = by * 128;
  __shared__ __align__(16) u16 SM[2 * 128 * 64];
  u16* As = SM;
  u16* Ws = SM + 128 * 64;

  int tid = threadIdx.x, lane = tid & 63, wid = tid >> 6;
  int wr = wid >> 1, wc = wid & 1;
  int l8 = lane >> 3;
  int sl = (lane & 7) ^ l8;

  f32x4 acc[4][4];
  #pragma unroll
  for (int i = 0; i < 4; ++i)
    #pragma unroll
    for (int j = 0; j < 4; ++j) acc[i][j] = (f32x4){0.f, 0.f, 0.f, 0.f};

  for (int k0 = 0; k0 < K; k0 += 64){
    #pragma unroll
    for (int j = 0; j < 4; ++j){
      int c = wid * 4 + j;
      const u16* ga = A  + (size_t)(m0 + 8*c + l8) * lda + k0 + sl*8;
      const u16* gw = Wt + (size_t)(n0 + 8*c + l8) * ldw + k0 + sl*8;
      __builtin_amdgcn_global_load_lds((const __attribute__((address_space(1))) void*)ga,
          (__attribute__((address_space(3))) void*)(As + c*512), 16, 0, 0);
      __builtin_amdgcn_global_load_lds((const __attribute__((address_space(1))) void*)gw,
          (__attribute__((address_space(3))) void*)(Ws + c*512), 16, 0, 0);
    }
    __syncthreads();
    #pragma unroll
    for (int kk = 0; kk < 2; ++kk){
      int slot = kk*4 + (lane >> 4);
      bf16x8 av[4], bv[4];
      #pragma unroll
      for (int mi = 0; mi < 4; ++mi){
        int r = wr*64 + mi*16 + (lane & 15);
        av[mi] = *(const bf16x8*)(As + r*64 + ((slot ^ (r & 7)) << 3));
      }
      #pragma unroll
      for (int ni = 0; ni < 4; ++ni){
        int r = wc*64 + ni*16 + (lane & 15);
        bv[ni] = *(const bf16x8*)(Ws + r*64 + ((slot ^ (r & 7)) << 3));
      }
      #pragma unroll
      for (int mi = 0; mi < 4; ++mi)
        #pragma unroll
        for (int ni = 0; ni < 4; ++ni)
          acc[mi][ni] = __builtin_amdgcn_mfma_f32_16x16x32_bf16(av[mi], bv[ni], acc[mi][ni], 0, 0, 0);
    }
    __syncthreads();
  }

  float* flds = (float*)SM;
  #pragma unroll
  for (int hf = 0; hf < 2; ++hf){
    if (wr == hf){
      #pragma unroll
      for (int mi = 0; mi < 4; ++mi){
        int rb = mi*16 + ((lane >> 4) << 2);
        #pragma unroll
        for (int ni = 0; ni < 4; ++ni){
          int colL = wc*64 + ni*16 + (lane & 15);
          #pragma unroll
          for (int r = 0; r < 4; ++r)
            flds[(rb + r)*128 + colL] = acc[mi][ni][r];
        }
      }
    }
    __syncthreads();
    int c = tid & 127;
    int gc = n0 + c;
    if (gc < N){
      for (int rr = (tid >> 7); rr < 64; rr += 2)
        C[(size_t)(m0 + hf*64 + rr) * ldc + gc] = flds[rr*128 + c];
    }
    __syncthreads();
  }
}

extern "C" void kernel_launch(void* const* d_in, const int* in_sizes, int n_in,
                              void* d_out, int out_size, void* d_ws, size_t ws_size,
                              hipStream_t stream)
{
  (void)in_sizes; (void)n_in; (void)out_size; (void)ws_size;
  const int* ids = (const int*)d_in[0];
  const void* tok = d_in[1];  const void* pos = d_in[2];
  const void* ln1g = d_in[3]; const void* ln1b = d_in[4];
  const void* wq = d_in[5];   const void* bq = d_in[6];
  const void* wk = d_in[7];   const void* bk = d_in[8];
  const void* wv = d_in[9];   const void* bv = d_in[10];
  const void* wo = d_in[11];  const void* bo = d_in[12];
  const void* ln2g = d_in[13]; const void* ln2b = d_in[14];
  const void* w1 = d_in[15];  const void* b1 = d_in[16];
  const void* w2 = d_in[17];  const void* b2 = d_in[18];
  const void* lnfg = d_in[19]; const void* lnfb = d_in[20];
  const void* pw = d_in[21];

  char* ob = (char*)d_out;
  float* logitsF = (float*)ob;
  float* attnF   = (float*)(ob + 411705344);
  float* x    = (float*)(ob + 100663296);
  u16* qkv    = (u16*)(ob + 106954752);
  u16* ctx    = (u16*)(ob + 116391936);
  u16* ff     = (u16*)(ob + 119537664);
  u16* wT     = (u16*)(ob + 132120576);
  u16* biascat= (u16*)(ob + 188743680);
  float* stats= (float*)(ob + 188762112);
  const long LSTR = 7077888;
  char* wsp = (char*)d_ws;
  int* dflag = (int*)wsp;
  u16* h      = (u16*)(wsp + 256);
  u16* chunkT = (u16*)(wsp + 256 + 3145728);

  const int BT = B_ * T_;
  detect_k<<<1, 256, 0, stream>>>((const u16*)tok, dflag);
  bcat_k<<<L_, 256, 0, stream>>>(bq, bk, bv, biascat, dflag);
  {
    dim3 gDD(24, 12, L_), g1(96, 12, L_), g2(24, 48, L_);
    transpose_k<<<gDD, 256, 0, stream>>>(wq, wT,            D_, D_,  D_,  0, (long)D_*D_,  LSTR, dflag);
    transpose_k<<<gDD, 256, 0, stream>>>(wk, wT + 589824,   D_, D_,  D_,  0, (long)D_*D_,  LSTR, dflag);
    transpose_k<<<gDD, 256, 0, stream>>>(wv, wT + 2*589824, D_, D_,  D_,  0, (long)D_*D_,  LSTR, dflag);
    transpose_k<<<gDD, 256, 0, stream>>>(wo, wT + 3*589824, D_, D_,  D_,  0, (long)D_*D_,  LSTR, dflag);
    transpose_k<<<g1, 256, 0, stream>>>(w1, wT + 4*589824,  D_, FF_, FF_, 0, (long)D_*FF_, LSTR, dflag);
    transpose_k<<<g2, 256, 0, stream>>>(w2, wT + 4*589824 + 2359296, FF_, D_, D_, 0, (long)FF_*D_, LSTR, dflag);
  }
  embed_k<<<BT, 256, 0, stream>>>(ids, tok, pos, x, dflag);

  dim3 gQKV(36, 16);
  dim3 gFF1(48, 16);
  dim3 gD2(12, 32, 2);               // split-K=2: 768 blocks (wo, ff2)
  dim3 gA(16, B_*H_);

  for (int l = 0; l < L_; ++l){
    long oB = (long)l * D_, oB1 = (long)l * FF_;
    u16* wl  = wT + (size_t)l * LSTR;
    u16* woT = wl + 3*589824;
    u16* w1T = wl + 4*589824;
    u16* w2T = w1T + 2359296;
    ln_k<<<BT, 256, 0, stream>>>(x, ln1g, ln1b, oB, h, dflag);
    gemmw_k<0><<<gQKV, 256, 0, stream>>>(h, wl, biascat, (long)l*3*D_, qkv, nullptr, nullptr,
        3*D_, D_, D_, D_, 3*D_);
    fattn_k<<<gA, 256, 0, stream>>>(qkv, ctx, stats);
    if (l == L_-1)
      probs_k<<<gA, 256, 0, stream>>>(qkv, stats, attnF);
    gemm_k<<<gD2, 256, 0, stream>>>(ctx, woT, bo, oB, x, dflag,
        D_, D_, D_, D_, D_);
    ln_k<<<BT, 256, 0, stream>>>(x, ln2g, ln2b, oB, h, dflag);
    gemmw_k<1><<<gFF1, 256, 0, stream>>>(h, w1T, b1, oB1, ff, nullptr, dflag,
        FF_, D_, D_, D_, FF_);
    gemm_k<<<gD2, 256, 0, stream>>>(ff, w2T, b2, oB, x, dflag,
        D_, FF_, FF_, FF_, D_);
  }
  ln_k<<<BT, 256, 0, stream>>>(x, lnfg, lnfb, 0, h, dflag);
  {
    const int CHUNK = 16384;   // 128 * 128
    int done = 0;
    while (done < V_){
      int cols = V_ - done; if (cols > CHUNK) cols = CHUNK;
      dim3 gt((cols + 31) / 32, 12);
      transpose_k<<<gt, 256, 0, stream>>>(pw, chunkT, D_, cols, V_, (long)done, 0, 0, dflag);
      int ny = (cols + 127) / 128;
      dim3 gp(16, ny);
      int swz = (ny % 8 == 0) ? 1 : 0;
      gemm128_k<<<gp, 256, 0, stream>>>(h, chunkT, logitsF + done, cols, D_, D_, D_, V_, swz);
      done += cols;
    }
  }
}

// Round 20
// 1076.032 us; speedup vs baseline: 1.0638x; 1.0017x over previous
//
#include <hip/hip_runtime.h>

typedef unsigned short u16;
typedef unsigned int u32;
typedef __bf16 bf16x8 __attribute__((ext_vector_type(8)));
typedef float f32x4 __attribute__((ext_vector_type(4)));

#define L_ 4
#define D_ 768
#define T_ 1024
#define B_ 2
#define H_ 12
#define DK_ 64
#define FF_ 3072
#define V_ 50257

__device__ __forceinline__ float bf2f(u16 u){ return __uint_as_float(((unsigned)u) << 16); }
__device__ __forceinline__ u16 f2bf(float f){
  unsigned x = __float_as_uint(f);
  return (u16)((x + 0x7fffu + ((x >> 16) & 1u)) >> 16);   // RNE
}

// ---- input dtype probe (HW-proven f32; kept as insurance) ----
__global__ __launch_bounds__(256) void detect_k(const u16* __restrict__ w, int* __restrict__ flag){
  __shared__ int s;
  if (threadIdx.x == 0) s = 0;
  __syncthreads();
  int bad = 0;
  for (int j = threadIdx.x; j < 4096; j += 256){
    int e = (w[j] >> 7) & 0xFF;
    if (e >= 0xC0) bad = 1;
  }
  if (bad) atomicOr(&s, 1);
  __syncthreads();
  if (threadIdx.x == 0) flag[0] = s;
}

__device__ __forceinline__ float rdin(const void* p, long i, bool wf){
  return wf ? ((const float*)p)[i] : bf2f(((const u16*)p)[i]);
}

// ---------------- embedding ----------------
__global__ __launch_bounds__(256) void embed_k(const int* __restrict__ ids,
    const void* __restrict__ tok, const void* __restrict__ pos, float* __restrict__ x,
    const int* __restrict__ dflag){
  bool wf = dflag[0] != 0;
  int row = blockIdx.x; int t = row & (T_-1);
  long id = ids[row];
  float* xr = x + (size_t)row * D_;
  for (int d = threadIdx.x; d < D_; d += 256)
    xr[d] = rdin(tok, id * (long)D_ + d, wf) + rdin(pos, (long)t * D_ + d, wf);
}

// ---------------- layernorm: f32 x -> bf16 h ----------------
__global__ __launch_bounds__(256) void ln_k(const float* __restrict__ x,
    const void* __restrict__ g, const void* __restrict__ bb, long goff, u16* __restrict__ out,
    const int* __restrict__ dflag){
  __shared__ float red[8];
  bool wf = dflag[0] != 0;
  int row = blockIdx.x, tid = threadIdx.x;
  const float* xr = x + (size_t)row * D_;
  float v[3]; float s = 0.f, s2 = 0.f;
  #pragma unroll
  for (int i = 0; i < 3; ++i){ float t = xr[tid + i*256]; v[i] = t; s += t; s2 += t*t; }
  #pragma unroll
  for (int o = 1; o < 64; o <<= 1){ s += __shfl_xor(s, o, 64); s2 += __shfl_xor(s2, o, 64); }
  if ((tid & 63) == 0){ red[tid >> 6] = s; red[(tid >> 6) + 4] = s2; }
  __syncthreads();
  s  = red[0] + red[1] + red[2] + red[3];
  s2 = red[4] + red[5] + red[6] + red[7];
  float mean = s * (1.f / D_);
  float var  = s2 * (1.f / D_) - mean * mean;
  float rstd = rsqrtf(var + 1e-5f);
  u16* orow = out + (size_t)row * D_;
  #pragma unroll
  for (int i = 0; i < 3; ++i){
    int d = tid + i*256;
    orow[d] = f2bf((v[i] - mean) * rstd * rdin(g, goff + d, wf) + rdin(bb, goff + d, wf));
  }
}

// ---------------- fused flash attention (ALL layers); emits per-row (m,l) stats ----------------
__global__ __launch_bounds__(256) void fattn_k(const u16* __restrict__ qkv, u16* __restrict__ ctx,
                                               float* __restrict__ stats){
  __shared__ __align__(16) u16 Qs[64][72];   // later reused as P
  __shared__ __align__(16) u16 Ks[64][72];
  __shared__ __align__(16) u16 Vt[64][72];   // V transposed: [d][k]
  int qb = 15 - blockIdx.x;
  int bh = blockIdx.y;
  int b = bh / H_, h = bh % H_;
  const u16* base = qkv + (size_t)b * T_ * 3*D_;
  int qoff = h*64, koff = D_ + h*64, voff = 2*D_ + h*64;
  int tid = threadIdx.x, lane = tid & 63, w = tid >> 6;
  int sr = tid >> 3, sc = (tid & 7) << 3;
  int l15 = lane & 15, lg = lane >> 4;

  {
    const u16* gq = base + (size_t)(qb*64 + sr) * 3*D_ + qoff + sc;
    *(int4*)(&Qs[sr][sc])      = *(const int4*)gq;
    *(int4*)(&Qs[sr + 32][sc]) = *(const int4*)(gq + (size_t)32 * 3*D_);
  }
  __syncthreads();
  bf16x8 aq[2];
  #pragma unroll
  for (int kk = 0; kk < 2; ++kk)
    aq[kk] = *(const bf16x8*)(&Qs[w*16 + l15][kk*32 + lg*8]);

  f32x4 oacc[4];
  #pragma unroll
  for (int i = 0; i < 4; ++i) oacc[i] = (f32x4){0.f,0.f,0.f,0.f};
  float m_run[4] = {-1e30f,-1e30f,-1e30f,-1e30f};
  float l_run[4] = {0.f,0.f,0.f,0.f};

  for (int kb = 0; kb <= qb; ++kb){
    __syncthreads();
    {
      const u16* gk = base + (size_t)(kb*64 + sr) * 3*D_ + koff + sc;
      *(int4*)(&Ks[sr][sc])      = *(const int4*)gk;
      *(int4*)(&Ks[sr + 32][sc]) = *(const int4*)(gk + (size_t)32 * 3*D_);
      const u16* gv = base + (size_t)(kb*64 + sr) * 3*D_ + voff + sc;
      u16 tmp[8];
      *(int4*)tmp = *(const int4*)gv;
      #pragma unroll
      for (int j = 0; j < 8; ++j) Vt[sc + j][sr] = tmp[j];
      *(int4*)tmp = *(const int4*)(gv + (size_t)32 * 3*D_);
      #pragma unroll
      for (int j = 0; j < 8; ++j) Vt[sc + j][sr + 32] = tmp[j];
    }
    __syncthreads();
    f32x4 sacc[4];
    #pragma unroll
    for (int i = 0; i < 4; ++i) sacc[i] = (f32x4){0.f,0.f,0.f,0.f};
    __builtin_amdgcn_s_setprio(1);
    #pragma unroll
    for (int kk = 0; kk < 2; ++kk){
      #pragma unroll
      for (int ni = 0; ni < 4; ++ni){
        bf16x8 bk = *(const bf16x8*)(&Ks[ni*16 + l15][kk*32 + lg*8]);
        sacc[ni] = __builtin_amdgcn_mfma_f32_16x16x32_bf16(aq[kk], bk, sacc[ni], 0, 0, 0);
      }
    }
    __builtin_amdgcn_s_setprio(0);
    #pragma unroll
    for (int ni = 0; ni < 4; ++ni)
      #pragma unroll
      for (int r = 0; r < 4; ++r){
        float s = sacc[ni][r] * 0.125f;
        if (kb == qb){
          int rowL = w*16 + lg*4 + r, colL = ni*16 + l15;
          if (colL > rowL) s = -1e30f;
        }
        sacc[ni][r] = s;
      }
    float mx[4], ps[4];
    #pragma unroll
    for (int r = 0; r < 4; ++r){
      float m = fmaxf(fmaxf(sacc[0][r], sacc[1][r]), fmaxf(sacc[2][r], sacc[3][r]));
      #pragma unroll
      for (int o = 1; o < 16; o <<= 1) m = fmaxf(m, __shfl_xor(m, o, 64));
      mx[r] = m;
    }
    #pragma unroll
    for (int r = 0; r < 4; ++r){
      float m_new = fmaxf(m_run[r], mx[r]);
      float alpha = expf(m_run[r] - m_new);
      float sum = 0.f;
      #pragma unroll
      for (int ni = 0; ni < 4; ++ni){
        float p = expf(sacc[ni][r] - m_new);
        sacc[ni][r] = p;
        sum += p;
      }
      #pragma unroll
      for (int o = 1; o < 16; o <<= 1) sum += __shfl_xor(sum, o, 64);
      m_run[r] = m_new;
      l_run[r] = l_run[r] * alpha + sum;
      ps[r] = alpha;
    }
    #pragma unroll
    for (int ni = 0; ni < 4; ++ni)
      #pragma unroll
      for (int r = 0; r < 4; ++r)
        oacc[ni][r] *= ps[r];
    #pragma unroll
    for (int ni = 0; ni < 4; ++ni)
      #pragma unroll
      for (int r = 0; r < 4; ++r)
        Qs[w*16 + lg*4 + r][ni*16 + l15] = f2bf(sacc[ni][r]);
    __builtin_amdgcn_s_setprio(1);
    #pragma unroll
    for (int kk = 0; kk < 2; ++kk){
      bf16x8 ap = *(const bf16x8*)(&Qs[w*16 + l15][kk*32 + lg*8]);
      #pragma unroll
      for (int ni = 0; ni < 4; ++ni){
        bf16x8 bv = *(const bf16x8*)(&Vt[ni*16 + l15][kk*32 + lg*8]);
        oacc[ni] = __builtin_amdgcn_mfma_f32_16x16x32_bf16(ap, bv, oacc[ni], 0, 0, 0);
      }
    }
    __builtin_amdgcn_s_setprio(0);
  }
  float inv[4];
  #pragma unroll
  for (int r = 0; r < 4; ++r) inv[r] = 1.f / l_run[r];
  #pragma unroll
  for (int ni = 0; ni < 4; ++ni){
    int col = h*64 + ni*16 + l15;
    #pragma unroll
    for (int r = 0; r < 4; ++r){
      int row = b*T_ + qb*64 + w*16 + lg*4 + r;
      ctx[(size_t)row * D_ + col] = f2bf(oacc[ni][r] * inv[r]);
    }
  }
  if (l15 == 0){
    float2* st = (float2*)stats;
    #pragma unroll
    for (int r = 0; r < 4; ++r){
      int row = qb*64 + w*16 + lg*4 + r;
      st[(size_t)bh * T_ + row] = make_float2(m_run[r], l_run[r]);
    }
  }
}

// ---------------- probs reconstruction (layer 3): attn = exp(QK^T/8 - m)/l, f32, full rows ----------------
__global__ __launch_bounds__(256) void probs_k(const u16* __restrict__ qkv,
    const float* __restrict__ stats, float* __restrict__ attnf){
  __shared__ __align__(16) u16 Qs[64][72];
  __shared__ __align__(16) u16 Ks[64][72];
  __shared__ float P[64][68];
  int qb = 15 - blockIdx.x;
  int bh = blockIdx.y;
  int b = bh / H_, h = bh % H_;
  const u16* base = qkv + (size_t)b * T_ * 3*D_;
  int qoff = h*64, koff = D_ + h*64;
  float* abase = attnf + (size_t)bh * T_ * T_;
  int tid = threadIdx.x, lane = tid & 63, w = tid >> 6;
  int sr = tid >> 3, sc = (tid & 7) << 3;
  int l15 = lane & 15, lg = lane >> 4;

  {
    const u16* gq = base + (size_t)(qb*64 + sr) * 3*D_ + qoff + sc;
    *(int4*)(&Qs[sr][sc])      = *(const int4*)gq;
    *(int4*)(&Qs[sr + 32][sc]) = *(const int4*)(gq + (size_t)32 * 3*D_);
  }
  __syncthreads();
  bf16x8 aq[2];
  #pragma unroll
  for (int kk = 0; kk < 2; ++kk)
    aq[kk] = *(const bf16x8*)(&Qs[w*16 + l15][kk*32 + lg*8]);
  float mrow[4], lirow[4];
  {
    const float2* st = (const float2*)stats;
    #pragma unroll
    for (int r = 0; r < 4; ++r){
      float2 s = st[(size_t)bh * T_ + qb*64 + w*16 + lg*4 + r];
      mrow[r] = s.x; lirow[r] = 1.f / s.y;
    }
  }

  for (int kb = 0; kb <= qb; ++kb){
    __syncthreads();
    {
      const u16* gk = base + (size_t)(kb*64 + sr) * 3*D_ + koff + sc;
      *(int4*)(&Ks[sr][sc])      = *(const int4*)gk;
      *(int4*)(&Ks[sr + 32][sc]) = *(const int4*)(gk + (size_t)32 * 3*D_);
    }
    __syncthreads();
    f32x4 sacc[4];
    #pragma unroll
    for (int i = 0; i < 4; ++i) sacc[i] = (f32x4){0.f,0.f,0.f,0.f};
    #pragma unroll
    for (int kk = 0; kk < 2; ++kk){
      #pragma unroll
      for (int ni = 0; ni < 4; ++ni){
        bf16x8 bk = *(const bf16x8*)(&Ks[ni*16 + l15][kk*32 + lg*8]);
        sacc[ni] = __builtin_amdgcn_mfma_f32_16x16x32_bf16(aq[kk], bk, sacc[ni], 0, 0, 0);
      }
    }
    #pragma unroll
    for (int ni = 0; ni < 4; ++ni)
      #pragma unroll
      for (int r = 0; r < 4; ++r){
        int rowL = w*16 + lg*4 + r, colL = ni*16 + l15;
        float p = expf(sacc[ni][r] * 0.125f - mrow[r]) * lirow[r];
        if (kb == qb && colL > rowL) p = 0.f;
        P[rowL][colL] = p;
      }
    __syncthreads();
    #pragma unroll
    for (int p4 = 0; p4 < 4; ++p4){
      int row = p4*16 + (tid >> 4);
      int c0 = tid & 15;
      float* dst = abase + (size_t)(qb*64 + row) * T_ + kb*64;
      #pragma unroll
      for (int j = 0; j < 4; ++j)
        dst[c0 + j*16] = P[row][c0 + j*16];
    }
  }
  for (int r = 0; r < 64; ++r){
    float* dst = abase + (size_t)(qb*64 + r) * T_;
    for (int k = (qb+1)*64 + tid; k < T_; k += 256) dst[k] = 0.f;
  }
}

// ---------------- transpose+convert (z-batched, 64Rx32C tile, vectorized writes) ----------------
__global__ __launch_bounds__(256) void transpose_k(const void* __restrict__ in, u16* __restrict__ outp,
                                                   int R, int C, int ldin, long ielem,
                                                   long zin, long zout,
                                                   const int* __restrict__ dflag){
  __shared__ u16 tile[32][72];
  bool wf = dflag[0] != 0;
  long zi = ielem + (long)blockIdx.z * zin;
  u16* op = outp + (size_t)blockIdx.z * zout;
  int c0 = blockIdx.x * 32, r0 = blockIdx.y * 64;
  int tid = threadIdx.x;
  int cl = tid & 31, rl = tid >> 5;
  int c = c0 + cl;
  bool okc = (c < C);
  #pragma unroll
  for (int p = 0; p < 8; ++p){
    int r = r0 + p*8 + rl;
    tile[cl][p*8 + rl] = okc ? f2bf(rdin(in, zi + (size_t)r * ldin + c, wf)) : (u16)0;
  }
  __syncthreads();
  int cs = tid >> 4, rs = (tid & 15) * 4;
  #pragma unroll
  for (int p = 0; p < 2; ++p){
    int cc = p*16 + cs;
    int cg = c0 + cc;
    if (cg < C){
      uint2 v = *(const uint2*)(&tile[cc][rs]);
      *(uint2*)(op + (size_t)cg * R + r0 + rs) = v;
    }
  }
}

// ---------------- qkv bias concat -> bf16 [L][2304] ----------------
__global__ __launch_bounds__(256) void bcat_k(const void* __restrict__ bq, const void* __restrict__ bk,
    const void* __restrict__ bv, u16* __restrict__ outp, const int* __restrict__ dflag){
  bool wf = dflag[0] != 0;
  int l = blockIdx.x;
  for (int j = threadIdx.x; j < 3*D_; j += 256){
    float v;
    if (j < D_)        v = rdin(bq, (long)l*D_ + j, wf);
    else if (j < 2*D_) v = rdin(bk, (long)l*D_ + j - D_, wf);
    else               v = rdin(bv, (long)l*D_ + j - 2*D_, wf);
    outp[(size_t)l*3*D_ + j] = f2bf(v);
  }
}

// ---------------- 64-tile GEMM (wo, ff2): split-K over blockIdx.z; atomic f32 += ----------------
__global__ __launch_bounds__(256) void gemm_k(
    const u16* __restrict__ A, const u16* __restrict__ W, const void* __restrict__ bias,
    long belem,
    float* __restrict__ Cf32, const int* __restrict__ dflag,
    int N, int K, int lda, int ldw, int ldc)
{
  int m0 = blockIdx.y * 64;
  int n0 = blockIdx.x * 64;
  const bool wf = dflag && (dflag[0] != 0);
  int Ks = K / gridDim.z;
  int koff = blockIdx.z * Ks;
  bool dob = (blockIdx.z == 0);

  __shared__ __align__(16) u16 SMEM[8192];
  u16* As = SMEM;
  u16* Ws = SMEM + 4096;

  int tid = threadIdx.x;
  int lane = tid & 63, wid = tid >> 6;
  int wr = wid >> 1, wc = wid & 1;
  int l15 = lane & 15, lg = lane >> 4;
  int l8 = lane >> 3;
  int sl = (lane & 7) ^ l8;

  f32x4 acc[2][2];
  #pragma unroll
  for (int i = 0; i < 2; ++i)
    #pragma unroll
    for (int j = 0; j < 2; ++j) acc[i][j] = (f32x4){0.f, 0.f, 0.f, 0.f};

  for (int k0 = koff; k0 < koff + Ks; k0 += 64){
    #pragma unroll
    for (int i = 0; i < 2; ++i){
      int rb = i*32 + wid*8;
      const u16* ga = A + (size_t)(m0 + rb + l8) * lda + k0 + sl*8;
      __builtin_amdgcn_global_load_lds((const __attribute__((address_space(1))) void*)ga,
          (__attribute__((address_space(3))) void*)(As + rb*64), 16, 0, 0);
      const u16* gw = W + (size_t)(n0 + rb + l8) * ldw + k0 + sl*8;
      __builtin_amdgcn_global_load_lds((const __attribute__((address_space(1))) void*)gw,
          (__attribute__((address_space(3))) void*)(Ws + rb*64), 16, 0, 0);
    }
    __syncthreads();
    #pragma unroll
    for (int kk = 0; kk < 2; ++kk){
      int slot = kk*4 + lg;
      bf16x8 af[2], bfr[2];
      #pragma unroll
      for (int mi = 0; mi < 2; ++mi){
        int r = wr*32 + mi*16 + l15;
        af[mi] = *(const bf16x8*)(As + r*64 + ((slot ^ (r & 7)) << 3));
      }
      #pragma unroll
      for (int ni = 0; ni < 2; ++ni){
        int r = wc*32 + ni*16 + l15;
        bfr[ni] = *(const bf16x8*)(Ws + r*64 + ((slot ^ (r & 7)) << 3));
      }
      #pragma unroll
      for (int mi = 0; mi < 2; ++mi)
        #pragma unroll
        for (int ni = 0; ni < 2; ++ni)
          acc[mi][ni] = __builtin_amdgcn_mfma_f32_16x16x32_bf16(af[mi], bfr[ni], acc[mi][ni], 0, 0, 0);
    }
    __syncthreads();
  }

  #pragma unroll
  for (int ni = 0; ni < 2; ++ni){
    int col = n0 + wc*32 + ni*16 + l15;
    float bvv = 0.f;
    if (dob && bias) bvv = wf ? ((const float*)bias)[belem + col] : bf2f(((const u16*)bias)[belem + col]);
    #pragma unroll
    for (int mi = 0; mi < 2; ++mi){
      int rbase = m0 + wr*32 + mi*16 + (lg << 2);
      #pragma unroll
      for (int r = 0; r < 4; ++r){
        int row = rbase + r;
        float v = acc[mi][ni][r] + bvv;
        atomicAdd(&Cf32[(size_t)row * ldc + col], v);
      }
    }
  }
}

// ---------------- 128(M)x64(N)-tile GEMM (qkv, ff1), bijective XCD swizzle ----------------
// swz: gridDim.y must be 16. o%8 = XCD; each XCD owns y in {2k, 2k+1} -> A chunk (384KB)
// and the full W (3.4-4.5MB) become L2-resident per XCD (T1).
template<int EPI>
__global__ __launch_bounds__(256) void gemmw_k(
    const u16* __restrict__ A, const u16* __restrict__ W, const void* __restrict__ bias,
    long belem,
    u16* __restrict__ Cbf, float* __restrict__ Cf32, const int* __restrict__ dflag,
    int N, int K, int lda, int ldw, int ldc)
{
  int gx = gridDim.x;
  int o = blockIdx.y * gx + blockIdx.x;
  int k = o & 7, j = o >> 3;
  int by = k*2 + j / gx;
  int bx = j % gx;
  int m0 = by * 128;
  int n0 = bx * 64;
  const bool wf = dflag && (dflag[0] != 0);

  __shared__ __align__(16) u16 SMEM[12288];
  u16* As = SMEM;
  u16* Ws = SMEM + 8192;

  int tid = threadIdx.x;
  int lane = tid & 63, wid = tid >> 6;
  int l15 = lane & 15, lg = lane >> 4;
  int l8 = lane >> 3;
  int sl = (lane & 7) ^ l8;

  f32x4 acc[2][4];
  #pragma unroll
  for (int i = 0; i < 2; ++i)
    #pragma unroll
    for (int j2 = 0; j2 < 4; ++j2) acc[i][j2] = (f32x4){0.f, 0.f, 0.f, 0.f};

  for (int k0 = 0; k0 < K; k0 += 64){
    #pragma unroll
    for (int j2 = 0; j2 < 4; ++j2){
      int rb = j2*32 + wid*8;
      const u16* ga = A + (size_t)(m0 + rb + l8) * lda + k0 + sl*8;
      __builtin_amdgcn_global_load_lds((const __attribute__((address_space(1))) void*)ga,
          (__attribute__((address_space(3))) void*)(As + rb*64), 16, 0, 0);
    }
    #pragma unroll
    for (int i = 0; i < 2; ++i){
      int rb = i*32 + wid*8;
      const u16* gw = W + (size_t)(n0 + rb + l8) * ldw + k0 + sl*8;
      __builtin_amdgcn_global_load_lds((const __attribute__((address_space(1))) void*)gw,
          (__attribute__((address_space(3))) void*)(Ws + rb*64), 16, 0, 0);
    }
    __syncthreads();
    #pragma unroll
    for (int kk = 0; kk < 2; ++kk){
      int slot = kk*4 + lg;
      bf16x8 af[2], bfr[4];
      #pragma unroll
      for (int mi = 0; mi < 2; ++mi){
        int r = wid*32 + mi*16 + l15;
        af[mi] = *(const bf16x8*)(As + r*64 + ((slot ^ (r & 7)) << 3));
      }
      #pragma unroll
      for (int ni = 0; ni < 4; ++ni){
        int r = ni*16 + l15;
        bfr[ni] = *(const bf16x8*)(Ws + r*64 + ((slot ^ (r & 7)) << 3));
      }
      #pragma unroll
      for (int mi = 0; mi < 2; ++mi)
        #pragma unroll
        for (int ni = 0; ni < 4; ++ni)
          acc[mi][ni] = __builtin_amdgcn_mfma_f32_16x16x32_bf16(af[mi], bfr[ni], acc[mi][ni], 0, 0, 0);
    }
    __syncthreads();
  }

  #pragma unroll
  for (int ni = 0; ni < 4; ++ni){
    int col = n0 + ni*16 + l15;
    float bvv = 0.f;
    if (bias) bvv = wf ? ((const float*)bias)[belem + col] : bf2f(((const u16*)bias)[belem + col]);
    #pragma unroll
    for (int mi = 0; mi < 2; ++mi){
      int rbase = m0 + wid*32 + mi*16 + (lg << 2);
      #pragma unroll
      for (int r = 0; r < 4; ++r){
        int row = rbase + r;
        float v = acc[mi][ni][r] + bvv;
        size_t idx = (size_t)row * ldc + col;
        if (EPI == 0)      Cbf[idx] = f2bf(v);
        else if (EPI == 1){ float gg = 0.5f * v * (1.f + erff(v * 0.70710678118654752f)); Cbf[idx] = f2bf(gg); }
        else               Cf32[idx] += v;
      }
    }
  }
}

// ---------------- 128x128 m97-structure GEMM: projection; XCD panel swizzle ----------------
__global__ __launch_bounds__(256) void gemm128_k(
    const u16* __restrict__ A, const u16* __restrict__ Wt, float* __restrict__ C,
    int N, int K, int lda, int ldw, int ldc, int swz)
{
  int bx, by;
  if (swz){
    int o = blockIdx.y * gridDim.x + blockIdx.x;
    int k = o & 7, j = o >> 3;
    bx = j & 15;
    by = k + 8 * (j >> 4);
  } else { bx = blockIdx.x; by = blockIdx.y; }
  int m0 = bx * 128;
  int n0 = by * 128;
  __shared__ __align__(16) u16 SM[2 * 128 * 64];
  u16* As = SM;
  u16* Ws = SM + 128 * 64;

  int tid = threadIdx.x, lane = tid & 63, wid = tid >> 6;
  int wr = wid >> 1, wc = wid & 1;
  int l8 = lane >> 3;
  int sl = (lane & 7) ^ l8;

  f32x4 acc[4][4];
  #pragma unroll
  for (int i = 0; i < 4; ++i)
    #pragma unroll
    for (int j = 0; j < 4; ++j) acc[i][j] = (f32x4){0.f, 0.f, 0.f, 0.f};

  for (int k0 = 0; k0 < K; k0 += 64){
    #pragma unroll
    for (int j = 0; j < 4; ++j){
      int c = wid * 4 + j;
      const u16* ga = A  + (size_t)(m0 + 8*c + l8) * lda + k0 + sl*8;
      const u16* gw = Wt + (size_t)(n0 + 8*c + l8) * ldw + k0 + sl*8;
      __builtin_amdgcn_global_load_lds((const __attribute__((address_space(1))) void*)ga,
          (__attribute__((address_space(3))) void*)(As + c*512), 16, 0, 0);
      __builtin_amdgcn_global_load_lds((const __attribute__((address_space(1))) void*)gw,
          (__attribute__((address_space(3))) void*)(Ws + c*512), 16, 0, 0);
    }
    __syncthreads();
    #pragma unroll
    for (int kk = 0; kk < 2; ++kk){
      int slot = kk*4 + (lane >> 4);
      bf16x8 av[4], bv[4];
      #pragma unroll
      for (int mi = 0; mi < 4; ++mi){
        int r = wr*64 + mi*16 + (lane & 15);
        av[mi] = *(const bf16x8*)(As + r*64 + ((slot ^ (r & 7)) << 3));
      }
      #pragma unroll
      for (int ni = 0; ni < 4; ++ni){
        int r = wc*64 + ni*16 + (lane & 15);
        bv[ni] = *(const bf16x8*)(Ws + r*64 + ((slot ^ (r & 7)) << 3));
      }
      #pragma unroll
      for (int mi = 0; mi < 4; ++mi)
        #pragma unroll
        for (int ni = 0; ni < 4; ++ni)
          acc[mi][ni] = __builtin_amdgcn_mfma_f32_16x16x32_bf16(av[mi], bv[ni], acc[mi][ni], 0, 0, 0);
    }
    __syncthreads();
  }

  float* flds = (float*)SM;
  #pragma unroll
  for (int hf = 0; hf < 2; ++hf){
    if (wr == hf){
      #pragma unroll
      for (int mi = 0; mi < 4; ++mi){
        int rb = mi*16 + ((lane >> 4) << 2);
        #pragma unroll
        for (int ni = 0; ni < 4; ++ni){
          int colL = wc*64 + ni*16 + (lane & 15);
          #pragma unroll
          for (int r = 0; r < 4; ++r)
            flds[(rb + r)*128 + colL] = acc[mi][ni][r];
        }
      }
    }
    __syncthreads();
    int c = tid & 127;
    int gc = n0 + c;
    if (gc < N){
      for (int rr = (tid >> 7); rr < 64; rr += 2)
        C[(size_t)(m0 + hf*64 + rr) * ldc + gc] = flds[rr*128 + c];
    }
    __syncthreads();
  }
}

extern "C" void kernel_launch(void* const* d_in, const int* in_sizes, int n_in,
                              void* d_out, int out_size, void* d_ws, size_t ws_size,
                              hipStream_t stream)
{
  (void)in_sizes; (void)n_in; (void)out_size; (void)ws_size;
  const int* ids = (const int*)d_in[0];
  const void* tok = d_in[1];  const void* pos = d_in[2];
  const void* ln1g = d_in[3]; const void* ln1b = d_in[4];
  const void* wq = d_in[5];   const void* bq = d_in[6];
  const void* wk = d_in[7];   const void* bk = d_in[8];
  const void* wv = d_in[9];   const void* bv = d_in[10];
  const void* wo = d_in[11];  const void* bo = d_in[12];
  const void* ln2g = d_in[13]; const void* ln2b = d_in[14];
  const void* w1 = d_in[15];  const void* b1 = d_in[16];
  const void* w2 = d_in[17];  const void* b2 = d_in[18];
  const void* lnfg = d_in[19]; const void* lnfb = d_in[20];
  const void* pw = d_in[21];

  char* ob = (char*)d_out;
  float* logitsF = (float*)ob;
  float* attnF   = (float*)(ob + 411705344);
  float* x    = (float*)(ob + 100663296);
  u16* qkv    = (u16*)(ob + 106954752);
  u16* ctx    = (u16*)(ob + 116391936);
  u16* ff     = (u16*)(ob + 119537664);
  u16* wT     = (u16*)(ob + 132120576);
  u16* biascat= (u16*)(ob + 188743680);
  float* stats= (float*)(ob + 188762112);
  const long LSTR = 7077888;
  char* wsp = (char*)d_ws;
  int* dflag = (int*)wsp;
  u16* h      = (u16*)(wsp + 256);
  u16* chunkT = (u16*)(wsp + 256 + 3145728);

  const int BT = B_ * T_;
  detect_k<<<1, 256, 0, stream>>>((const u16*)tok, dflag);
  bcat_k<<<L_, 256, 0, stream>>>(bq, bk, bv, biascat, dflag);
  {
    dim3 gDD(24, 12, L_), g1(96, 12, L_), g2(24, 48, L_);
    transpose_k<<<gDD, 256, 0, stream>>>(wq, wT,            D_, D_,  D_,  0, (long)D_*D_,  LSTR, dflag);
    transpose_k<<<gDD, 256, 0, stream>>>(wk, wT + 589824,   D_, D_,  D_,  0, (long)D_*D_,  LSTR, dflag);
    transpose_k<<<gDD, 256, 0, stream>>>(wv, wT + 2*589824, D_, D_,  D_,  0, (long)D_*D_,  LSTR, dflag);
    transpose_k<<<gDD, 256, 0, stream>>>(wo, wT + 3*589824, D_, D_,  D_,  0, (long)D_*D_,  LSTR, dflag);
    transpose_k<<<g1, 256, 0, stream>>>(w1, wT + 4*589824,  D_, FF_, FF_, 0, (long)D_*FF_, LSTR, dflag);
    transpose_k<<<g2, 256, 0, stream>>>(w2, wT + 4*589824 + 2359296, FF_, D_, D_, 0, (long)FF_*D_, LSTR, dflag);
  }
  embed_k<<<BT, 256, 0, stream>>>(ids, tok, pos, x, dflag);

  dim3 gQKV(36, 16);
  dim3 gFF1(48, 16);
  dim3 gD2(12, 32, 2);               // split-K=2: 768 blocks (wo, ff2)
  dim3 gA(16, B_*H_);

  for (int l = 0; l < L_; ++l){
    long oB = (long)l * D_, oB1 = (long)l * FF_;
    u16* wl  = wT + (size_t)l * LSTR;
    u16* woT = wl + 3*589824;
    u16* w1T = wl + 4*589824;
    u16* w2T = w1T + 2359296;
    ln_k<<<BT, 256, 0, stream>>>(x, ln1g, ln1b, oB, h, dflag);
    gemmw_k<0><<<gQKV, 256, 0, stream>>>(h, wl, biascat, (long)l*3*D_, qkv, nullptr, nullptr,
        3*D_, D_, D_, D_, 3*D_);
    fattn_k<<<gA, 256, 0, stream>>>(qkv, ctx, stats);
    if (l == L_-1)
      probs_k<<<gA, 256, 0, stream>>>(qkv, stats, attnF);
    gemm_k<<<gD2, 256, 0, stream>>>(ctx, woT, bo, oB, x, dflag,
        D_, D_, D_, D_, D_);
    ln_k<<<BT, 256, 0, stream>>>(x, ln2g, ln2b, oB, h, dflag);
    gemmw_k<1><<<gFF1, 256, 0, stream>>>(h, w1T, b1, oB1, ff, nullptr, dflag,
        FF_, D_, D_, D_, FF_);
    gemm_k<<<gD2, 256, 0, stream>>>(ff, w2T, b2, oB, x, dflag,
        D_, FF_, FF_, FF_, D_);
  }
  ln_k<<<BT, 256, 0, stream>>>(x, lnfg, lnfb, 0, h, dflag);
  {
    const int CHUNK = 16384;   // 128 * 128
    int done = 0;
    while (done < V_){
      int cols = V_ - done; if (cols > CHUNK) cols = CHUNK;
      dim3 gt((cols + 31) / 32, 12);
      transpose_k<<<gt, 256, 0, stream>>>(pw, chunkT, D_, cols, V_, (long)done, 0, 0, dflag);
      int ny = (cols + 127) / 128;
      dim3 gp(16, ny);
      int swz = (ny % 8 == 0) ? 1 : 0;
      gemm128_k<<<gp, 256, 0, stream>>>(h, chunkT, logitsF + done, cols, D_, D_, D_, V_, swz);
      done += cols;
    }
  }
}